// Round 2
// baseline (518.708 us; speedup 1.0000x reference)
//
#include <hip/hip_runtime.h>

typedef __bf16 bf16;
typedef __bf16 bf16x8 __attribute__((ext_vector_type(8)));
typedef float f32x4 __attribute__((ext_vector_type(4)));

#define DEV static __device__ __forceinline__

constexpr int S  = 2048;
constexpr int D  = 2048;
constexpr int H  = 32;
constexpr int G  = 8;
constexpr int HD = 64;
constexpr int NQG = 2 * H * HD;  // 4096 (q+gate channels)
constexpr int NKV = G * HD;      // 512

DEV bf16x8 load8(const bf16* p) { return *reinterpret_cast<const bf16x8*>(p); }

DEV f32x4 mfma16(bf16x8 a, bf16x8 b, f32x4 c) {
  return __builtin_amdgcn_mfma_f32_16x16x32_bf16(a, b, c, 0, 0, 0);
}

// ---------------------------------------------------------------------------
// f32 -> bf16 conversion (inputs arrive as float32 per the reference).
// Each thread converts 8 elements. n must be a multiple of 8 (all ours are).
// ---------------------------------------------------------------------------
__global__ __launch_bounds__(256) void cvt_f32_bf16(
    const float* __restrict__ in, bf16* __restrict__ out, int n)
{
  int i = (int)(blockIdx.x * 256u + threadIdx.x) * 8;
  if (i >= n) return;
  const float4* p = reinterpret_cast<const float4*>(in + i);
  float4 a = p[0], b = p[1];
  bf16x8 o;
  o[0] = (bf16)a.x; o[1] = (bf16)a.y; o[2] = (bf16)a.z; o[3] = (bf16)a.w;
  o[4] = (bf16)b.x; o[5] = (bf16)b.y; o[6] = (bf16)b.z; o[7] = (bf16)b.w;
  *reinterpret_cast<bf16x8*>(out + i) = o;
}

// ---------------------------------------------------------------------------
// Fused QKV projection: C = X @ W^T for W in {Wq (4096,2048), Wk, Wv (512,2048)}
// grid = (80, 8), block = 256 (4 waves). Each wave computes a 64x64 tile.
// nt 0..63 -> qg, 64..71 -> kpre, 72..79 -> v written TRANSPOSED into vt[d][s].
// ---------------------------------------------------------------------------
__global__ __launch_bounds__(256) void gemm_qkv(
    const bf16* __restrict__ X, const bf16* __restrict__ Wq,
    const bf16* __restrict__ Wk, const bf16* __restrict__ Wv,
    bf16* __restrict__ qg, bf16* __restrict__ kpre, bf16* __restrict__ vt)
{
  const int wave = threadIdx.x >> 6;
  const int lane = threadIdx.x & 63;
  const int ln = lane & 15, hi = lane >> 4;
  const int m0 = blockIdx.y * 256 + wave * 64;
  const int nt = blockIdx.x;

  const bf16* W; int n0;
  if (nt < 64)      { W = Wq; n0 = nt * 64; }
  else if (nt < 72) { W = Wk; n0 = (nt - 64) * 64; }
  else              { W = Wv; n0 = (nt - 72) * 64; }

  f32x4 acc[4][4] = {};
  const bf16* ap = X + (size_t)(m0 + ln) * D + hi * 8;
  const bf16* bp = W + (size_t)(n0 + ln) * D + hi * 8;

  for (int k0 = 0; k0 < D; k0 += 32) {
    bf16x8 a[4], b[4];
#pragma unroll
    for (int i = 0; i < 4; ++i) {
      a[i] = load8(ap + i * 16 * D + k0);
      b[i] = load8(bp + i * 16 * D + k0);
    }
#pragma unroll
    for (int mi = 0; mi < 4; ++mi)
#pragma unroll
      for (int ni = 0; ni < 4; ++ni)
        acc[mi][ni] = mfma16(a[mi], b[ni], acc[mi][ni]);
  }

  if (nt < 72) {
    bf16* C; int ldc;
    if (nt < 64) { C = qg; ldc = NQG; } else { C = kpre; ldc = NKV; }
#pragma unroll
    for (int mi = 0; mi < 4; ++mi)
#pragma unroll
      for (int ni = 0; ni < 4; ++ni)
#pragma unroll
        for (int j = 0; j < 4; ++j) {
          int r = m0 + mi * 16 + hi * 4 + j;
          int c = n0 + ni * 16 + ln;
          C[(size_t)r * ldc + c] = (bf16)acc[mi][ni][j];
        }
  } else {
    // V: write transposed vt[channel][s]
#pragma unroll
    for (int mi = 0; mi < 4; ++mi)
#pragma unroll
      for (int ni = 0; ni < 4; ++ni)
#pragma unroll
        for (int j = 0; j < 4; ++j) {
          int r = m0 + mi * 16 + hi * 4 + j;       // s
          int c = n0 + ni * 16 + ln;               // channel
          vt[(size_t)c * S + r] = (bf16)acc[mi][ni][j];
        }
  }
}

// ---------------------------------------------------------------------------
// RMSNorm + RoPE for q (32 heads) and k (8 groups). One wave per vector,
// lane = d in [0,64). hh < 32 -> q head, else k group (hh-32).
// cos/sin and norm weights are f32 (as in the reference).
// q written qrot[h][s][d]; k written krot[g][s][d]  (bf16 for MFMA input).
// ---------------------------------------------------------------------------
__global__ __launch_bounds__(256) void rmsrope(
    const bf16* __restrict__ qg, const bf16* __restrict__ kpre,
    const float* __restrict__ cosb, const float* __restrict__ sinb,
    const float* __restrict__ qw, const float* __restrict__ kw,
    bf16* __restrict__ qrot, bf16* __restrict__ krot)
{
  int wid  = (int)((blockIdx.x * (unsigned)blockDim.x + threadIdx.x) >> 6);
  int lane = threadIdx.x & 63;
  int s  = wid & (S - 1);
  int hh = wid >> 11;  // 0..39

  float v, wgt;
  if (hh < H) { v = (float)qg[(size_t)s * NQG + hh * 128 + lane];        wgt = qw[lane]; }
  else        { v = (float)kpre[(size_t)s * NKV + (hh - H) * 64 + lane]; wgt = kw[lane]; }

  float ss = v * v;
#pragma unroll
  for (int m = 1; m < 64; m <<= 1) ss += __shfl_xor(ss, m);
  float xf = v * (1.0f / sqrtf(ss * (1.0f / 64.0f) + 1e-6f)) * (1.0f + wgt);

  float part = __shfl_xor(xf, 32);
  float rot  = (lane < 32) ? -part : part;
  float c  = cosb[(size_t)s * HD + lane];
  float sn = sinb[(size_t)s * HD + lane];
  bf16 outv = (bf16)(xf * c + rot * sn);

  if (hh < H) qrot[((size_t)hh * S + s) * HD + lane] = outv;
  else        krot[((size_t)(hh - H) * S + s) * HD + lane] = outv;
}

// ---------------------------------------------------------------------------
// Causal flash attention + sigmoid gating.
// grid = H * S/64 = 1024 blocks, 4 waves. Wave owns 16 queries.
// Per 32-key tile: QK^T (2x2 MFMA), online softmax (16-lane shfl reduces),
// P staged bf16 in stride-40 LDS, PV (4 MFMA, K=32).
// ---------------------------------------------------------------------------
__global__ __launch_bounds__(256) void attn(
    const bf16* __restrict__ qrot, const bf16* __restrict__ krot,
    const bf16* __restrict__ vt, const bf16* __restrict__ qg,
    bf16* __restrict__ ctxg)
{
  __shared__ __align__(16) bf16 Pl[4][16 * 40];
  const int wave = threadIdx.x >> 6;
  const int lane = threadIdx.x & 63;
  const int ln = lane & 15, hi = lane >> 4;
  const int h    = blockIdx.x >> 5;
  const int qblk = blockIdx.x & 31;
  const int g    = h >> 2;  // GS = 4
  const int qb   = qblk * 64 + wave * 16;

  bf16x8 aq0 = load8(qrot + ((size_t)h * S + qb + ln) * HD + hi * 8);
  bf16x8 aq1 = load8(qrot + ((size_t)h * S + qb + ln) * HD + 32 + hi * 8);

  f32x4 po[4] = {};
  float mj[4] = {-INFINITY, -INFINITY, -INFINITY, -INFINITY};
  float lj[4] = {0.f, 0.f, 0.f, 0.f};
  const float scale = 0.125f;  // HD^-0.5

  bf16* pw = &Pl[wave][0];

  for (int key0 = 0; key0 <= qb + 15; key0 += 32) {
    const bf16* kb = krot + ((size_t)g * S + key0) * HD;
    bf16x8 bk00 = load8(kb + ln * HD + hi * 8);
    bf16x8 bk01 = load8(kb + ln * HD + 32 + hi * 8);
    bf16x8 bk10 = load8(kb + (16 + ln) * HD + hi * 8);
    bf16x8 bk11 = load8(kb + (16 + ln) * HD + 32 + hi * 8);

    f32x4 s0 = {}, s1 = {};
    s0 = mfma16(aq0, bk00, s0);
    s0 = mfma16(aq1, bk01, s0);
    s1 = mfma16(aq0, bk10, s1);
    s1 = mfma16(aq1, bk11, s1);

    float p0[4], p1[4], cj[4];
#pragma unroll
    for (int j = 0; j < 4; ++j) {
      int qd = qb + hi * 4 + j;
      float v0 = (key0 + ln      <= qd) ? s0[j] * scale : -INFINITY;
      float v1 = (key0 + 16 + ln <= qd) ? s1[j] * scale : -INFINITY;
      float tm = fmaxf(v0, v1);
#pragma unroll
      for (int m = 1; m < 16; m <<= 1) tm = fmaxf(tm, __shfl_xor(tm, m));
      float mn = fmaxf(mj[j], tm);
      float c  = __expf(mj[j] - mn);
      float e0 = __expf(v0 - mn);
      float e1 = __expf(v1 - mn);
      float ps = e0 + e1;
#pragma unroll
      for (int m = 1; m < 16; m <<= 1) ps += __shfl_xor(ps, m);
      lj[j] = lj[j] * c + ps;
      mj[j] = mn; cj[j] = c;
      p0[j] = e0; p1[j] = e1;
    }

#pragma unroll
    for (int dt = 0; dt < 4; ++dt) {
      f32x4 t = po[dt];
#pragma unroll
      for (int j = 0; j < 4; ++j) t[j] *= cj[j];
      po[dt] = t;
    }

#pragma unroll
    for (int j = 0; j < 4; ++j) {
      pw[(hi * 4 + j) * 40 + ln]      = (bf16)p0[j];
      pw[(hi * 4 + j) * 40 + 16 + ln] = (bf16)p1[j];
    }

    bf16x8 pa = load8(pw + ln * 40 + hi * 8);
#pragma unroll
    for (int dt = 0; dt < 4; ++dt) {
      bf16x8 bv = load8(vt + ((size_t)g * 64 + dt * 16 + ln) * S + key0 + hi * 8);
      po[dt] = mfma16(pa, bv, po[dt]);
    }
  }

  // epilogue: normalize, gate, store ctx_gated[s][h*64+d]
#pragma unroll
  for (int dt = 0; dt < 4; ++dt)
#pragma unroll
    for (int j = 0; j < 4; ++j) {
      int q = qb + hi * 4 + j;
      int d = dt * 16 + ln;
      float o  = po[dt][j] / lj[j];
      float gv = (float)qg[(size_t)q * NQG + h * 128 + 64 + d];
      float sg = 1.0f / (1.0f + __expf(-gv));
      ctxg[(size_t)q * D + h * 64 + d] = (bf16)(o * sg);
    }
}

// ---------------------------------------------------------------------------
// Output projection: out = ctx_gated @ Wo^T  (Wo is (2048,2048) row-major).
// Output written as FLOAT32 (the reference's output dtype).
// grid = (32, 8), block = 256.
// ---------------------------------------------------------------------------
__global__ __launch_bounds__(256) void gemm_out(
    const bf16* __restrict__ A, const bf16* __restrict__ W,
    float* __restrict__ C)
{
  const int wave = threadIdx.x >> 6;
  const int lane = threadIdx.x & 63;
  const int ln = lane & 15, hi = lane >> 4;
  const int m0 = blockIdx.y * 256 + wave * 64;
  const int n0 = blockIdx.x * 64;

  f32x4 acc[4][4] = {};
  const bf16* ap = A + (size_t)(m0 + ln) * D + hi * 8;
  const bf16* bp = W + (size_t)(n0 + ln) * D + hi * 8;

  for (int k0 = 0; k0 < D; k0 += 32) {
    bf16x8 a[4], b[4];
#pragma unroll
    for (int i = 0; i < 4; ++i) {
      a[i] = load8(ap + i * 16 * D + k0);
      b[i] = load8(bp + i * 16 * D + k0);
    }
#pragma unroll
    for (int mi = 0; mi < 4; ++mi)
#pragma unroll
      for (int ni = 0; ni < 4; ++ni)
        acc[mi][ni] = mfma16(a[mi], b[ni], acc[mi][ni]);
  }

#pragma unroll
  for (int mi = 0; mi < 4; ++mi)
#pragma unroll
    for (int ni = 0; ni < 4; ++ni)
#pragma unroll
      for (int j = 0; j < 4; ++j) {
        int r = m0 + mi * 16 + hi * 4 + j;
        int c = n0 + ni * 16 + ln;
        C[(size_t)r * D + c] = acc[mi][ni][j];
      }
}

// ---------------------------------------------------------------------------
extern "C" void kernel_launch(void* const* d_in, const int* in_sizes, int n_in,
                              void* d_out, int out_size, void* d_ws, size_t ws_size,
                              hipStream_t stream) {
  const float* x    = (const float*)d_in[0];
  // d_in[1] = mask (bool) — causal triu(k=1), computed analytically instead
  const float* cosb = (const float*)d_in[2];
  const float* sinb = (const float*)d_in[3];
  const float* Wq   = (const float*)d_in[4];
  const float* Wk   = (const float*)d_in[5];
  const float* Wv   = (const float*)d_in[6];
  const float* Wo   = (const float*)d_in[7];
  const float* qw   = (const float*)d_in[8];
  const float* kw   = (const float*)d_in[9];

  char* ws = (char*)d_ws;
  bf16* xb   = (bf16*)(ws);                       //  8 MB (2048x2048)
  bf16* Wqb  = (bf16*)(ws + ( 8u << 20));         // 16 MB (4096x2048)
  bf16* Wkb  = (bf16*)(ws + (24u << 20));         //  2 MB (512x2048)
  bf16* Wvb  = (bf16*)(ws + (26u << 20));         //  2 MB
  bf16* Wob  = (bf16*)(ws + (28u << 20));         //  8 MB (2048x2048)
  bf16* qg   = (bf16*)(ws + (36u << 20));         // 16 MB (2048x4096)
  bf16* kpre = (bf16*)(ws + (52u << 20));         //  2 MB
  bf16* vt   = (bf16*)(ws + (54u << 20));         //  2 MB  [channel][s]
  bf16* qrot = (bf16*)(ws + (56u << 20));         //  8 MB  [h][s][d]
  bf16* krot = (bf16*)(ws + (64u << 20));         //  2 MB  [g][s][d]
  bf16* ctxg = (bf16*)(ws + (66u << 20));         //  8 MB
  float* out = (float*)d_out;

  cvt_f32_bf16<<<dim3(2048), 256, 0, stream>>>(x,  xb,  S * D);
  cvt_f32_bf16<<<dim3(4096), 256, 0, stream>>>(Wq, Wqb, NQG * D);
  cvt_f32_bf16<<<dim3(512),  256, 0, stream>>>(Wk, Wkb, NKV * D);
  cvt_f32_bf16<<<dim3(512),  256, 0, stream>>>(Wv, Wvb, NKV * D);
  cvt_f32_bf16<<<dim3(2048), 256, 0, stream>>>(Wo, Wob, D * D);

  gemm_qkv<<<dim3(80, 8), 256, 0, stream>>>(xb, Wqb, Wkb, Wvb, qg, kpre, vt);
  rmsrope<<<dim3(20480), 256, 0, stream>>>(qg, kpre, cosb, sinb, qw, kw, qrot, krot);
  attn<<<dim3(1024), 256, 0, stream>>>(qrot, krot, vt, qg, ctxg);
  gemm_out<<<dim3(32, 8), 256, 0, stream>>>(ctxg, Wob, out);
}

// Round 3
// 412.578 us; speedup vs baseline: 1.2572x; 1.2572x over previous
//
#include <hip/hip_runtime.h>

typedef __bf16 bf16;
typedef __bf16 bf16x4 __attribute__((ext_vector_type(4)));
typedef __bf16 bf16x8 __attribute__((ext_vector_type(8)));
typedef float f32x4 __attribute__((ext_vector_type(4)));

#define DEV static __device__ __forceinline__

constexpr int S  = 2048;
constexpr int D  = 2048;
constexpr int H  = 32;
constexpr int G  = 8;
constexpr int HD = 64;
constexpr int NQG = 2 * H * HD;  // 4096 (q+gate channels)
constexpr int NKV = G * HD;      // 512
constexpr int LDP = 72;          // padded LDS row stride (elements) for P tile

DEV bf16x8 load8(const bf16* p) { return *reinterpret_cast<const bf16x8*>(p); }

DEV f32x4 mfma16(bf16x8 a, bf16x8 b, f32x4 c) {
  return __builtin_amdgcn_mfma_f32_16x16x32_bf16(a, b, c, 0, 0, 0);
}

// ---------------------------------------------------------------------------
// f32 -> bf16 conversion.
// ---------------------------------------------------------------------------
__global__ __launch_bounds__(256) void cvt_f32_bf16(
    const float* __restrict__ in, bf16* __restrict__ out, int n)
{
  int i = (int)(blockIdx.x * 256u + threadIdx.x) * 8;
  if (i >= n) return;
  const float4* p = reinterpret_cast<const float4*>(in + i);
  float4 a = p[0], b = p[1];
  bf16x8 o;
  o[0] = (bf16)a.x; o[1] = (bf16)a.y; o[2] = (bf16)a.z; o[3] = (bf16)a.w;
  o[4] = (bf16)b.x; o[5] = (bf16)b.y; o[6] = (bf16)b.z; o[7] = (bf16)b.w;
  *reinterpret_cast<bf16x8*>(out + i) = o;
}

// ---------------------------------------------------------------------------
// Fused QKV projection (unchanged from passing round).
// ---------------------------------------------------------------------------
__global__ __launch_bounds__(256) void gemm_qkv(
    const bf16* __restrict__ X, const bf16* __restrict__ Wq,
    const bf16* __restrict__ Wk, const bf16* __restrict__ Wv,
    bf16* __restrict__ qg, bf16* __restrict__ kpre, bf16* __restrict__ vt)
{
  const int wave = threadIdx.x >> 6;
  const int lane = threadIdx.x & 63;
  const int ln = lane & 15, hi = lane >> 4;
  const int m0 = blockIdx.y * 256 + wave * 64;
  const int nt = blockIdx.x;

  const bf16* W; int n0;
  if (nt < 64)      { W = Wq; n0 = nt * 64; }
  else if (nt < 72) { W = Wk; n0 = (nt - 64) * 64; }
  else              { W = Wv; n0 = (nt - 72) * 64; }

  f32x4 acc[4][4] = {};
  const bf16* ap = X + (size_t)(m0 + ln) * D + hi * 8;
  const bf16* bp = W + (size_t)(n0 + ln) * D + hi * 8;

  for (int k0 = 0; k0 < D; k0 += 32) {
    bf16x8 a[4], b[4];
#pragma unroll
    for (int i = 0; i < 4; ++i) {
      a[i] = load8(ap + i * 16 * D + k0);
      b[i] = load8(bp + i * 16 * D + k0);
    }
#pragma unroll
    for (int mi = 0; mi < 4; ++mi)
#pragma unroll
      for (int ni = 0; ni < 4; ++ni)
        acc[mi][ni] = mfma16(a[mi], b[ni], acc[mi][ni]);
  }

  if (nt < 72) {
    bf16* C; int ldc;
    if (nt < 64) { C = qg; ldc = NQG; } else { C = kpre; ldc = NKV; }
#pragma unroll
    for (int mi = 0; mi < 4; ++mi)
#pragma unroll
      for (int ni = 0; ni < 4; ++ni)
#pragma unroll
        for (int j = 0; j < 4; ++j) {
          int r = m0 + mi * 16 + hi * 4 + j;
          int c = n0 + ni * 16 + ln;
          C[(size_t)r * ldc + c] = (bf16)acc[mi][ni][j];
        }
  } else {
#pragma unroll
    for (int mi = 0; mi < 4; ++mi)
#pragma unroll
      for (int ni = 0; ni < 4; ++ni)
#pragma unroll
        for (int j = 0; j < 4; ++j) {
          int r = m0 + mi * 16 + hi * 4 + j;       // s
          int c = n0 + ni * 16 + ln;               // channel
          vt[(size_t)c * S + r] = (bf16)acc[mi][ni][j];
        }
  }
}

// ---------------------------------------------------------------------------
// RMSNorm + RoPE (unchanged).
// ---------------------------------------------------------------------------
__global__ __launch_bounds__(256) void rmsrope(
    const bf16* __restrict__ qg, const bf16* __restrict__ kpre,
    const float* __restrict__ cosb, const float* __restrict__ sinb,
    const float* __restrict__ qw, const float* __restrict__ kw,
    bf16* __restrict__ qrot, bf16* __restrict__ krot)
{
  int wid  = (int)((blockIdx.x * (unsigned)blockDim.x + threadIdx.x) >> 6);
  int lane = threadIdx.x & 63;
  int s  = wid & (S - 1);
  int hh = wid >> 11;  // 0..39

  float v, wgt;
  if (hh < H) { v = (float)qg[(size_t)s * NQG + hh * 128 + lane];        wgt = qw[lane]; }
  else        { v = (float)kpre[(size_t)s * NKV + (hh - H) * 64 + lane]; wgt = kw[lane]; }

  float ss = v * v;
#pragma unroll
  for (int m = 1; m < 64; m <<= 1) ss += __shfl_xor(ss, m);
  float xf = v * (1.0f / sqrtf(ss * (1.0f / 64.0f) + 1e-6f)) * (1.0f + wgt);

  float part = __shfl_xor(xf, 32);
  float rot  = (lane < 32) ? -part : part;
  float c  = cosb[(size_t)s * HD + lane];
  float sn = sinb[(size_t)s * HD + lane];
  bf16 outv = (bf16)(xf * c + rot * sn);

  if (hh < H) qrot[((size_t)hh * S + s) * HD + lane] = outv;
  else        krot[((size_t)(hh - H) * S + s) * HD + lane] = outv;
}

// ---------------------------------------------------------------------------
// Flash attention, swapped-QK^T formulation.
// Each wave: 16 queries (q = qb + ln for softmax state), 64-key tiles.
// QK^T = mfma(Kfrag, Qfrag) -> lane ln holds 16 scores of query qb+ln
//   (keys kr*16 + hi*4 + j). Row reduce = 15 in-reg ops + 2 shfl_xor.
// P transposed through padded wave-private LDS for the PV A-operand.
// Blocks pair q-block pr with 31-pr: every block = exactly 33 key-tiles.
// ---------------------------------------------------------------------------
DEV void attn_qtile(const bf16* __restrict__ qrot, const bf16* __restrict__ krot,
                    const bf16* __restrict__ vt, const bf16* __restrict__ qg,
                    bf16* __restrict__ ctxg, bf16* pw,
                    int h, int g, int qb, int ln, int hi)
{
  const float scale2 = 0.18033688011111204f;  // 0.125 * log2(e)

  const bf16* qbase = qrot + ((size_t)h * S + qb + ln) * HD + hi * 8;
  bf16x8 q0 = load8(qbase);
  bf16x8 q1 = load8(qbase + 32);

  f32x4 po[4] = {};
  float m = -INFINITY, l = 0.f;
  const int q = qb + ln;
  const int ntiles = (qb >> 6) + 1;

  for (int t = 0; t < ntiles; ++t) {
    const int key0 = t << 6;
    const bf16* kb = krot + ((size_t)g * S + key0) * HD;

    bf16x8 kf0[4], kf1[4];
#pragma unroll
    for (int kr = 0; kr < 4; ++kr) {
      kf0[kr] = load8(kb + (kr * 16 + ln) * HD + hi * 8);
      kf1[kr] = load8(kb + (kr * 16 + ln) * HD + 32 + hi * 8);
    }
    bf16x8 bv0[4], bv1[4];
#pragma unroll
    for (int dt = 0; dt < 4; ++dt) {
      const bf16* vb = vt + ((size_t)g * 64 + dt * 16 + ln) * S + key0 + hi * 8;
      bv0[dt] = load8(vb);
      bv1[dt] = load8(vb + 32);
    }

    f32x4 sc[4] = {};
#pragma unroll
    for (int kr = 0; kr < 4; ++kr) {
      sc[kr] = mfma16(kf0[kr], q0, sc[kr]);
      sc[kr] = mfma16(kf1[kr], q1, sc[kr]);
    }

    // mask + scale (log2 domain), running max
    float pmax = -INFINITY;
#pragma unroll
    for (int kr = 0; kr < 4; ++kr)
#pragma unroll
      for (int j = 0; j < 4; ++j) {
        int key = key0 + kr * 16 + hi * 4 + j;
        float v = (key <= q) ? sc[kr][j] * scale2 : -INFINITY;
        sc[kr][j] = v;
        pmax = fmaxf(pmax, v);
      }
    pmax = fmaxf(pmax, __shfl_xor(pmax, 16));
    pmax = fmaxf(pmax, __shfl_xor(pmax, 32));
    float mn = fmaxf(m, pmax);
    float c = exp2f(m - mn);
    m = mn;

    float ps = 0.f;
#pragma unroll
    for (int kr = 0; kr < 4; ++kr)
#pragma unroll
      for (int j = 0; j < 4; ++j) {
        float e = exp2f(sc[kr][j] - mn);
        sc[kr][j] = e;
        ps += e;
      }
    ps += __shfl_xor(ps, 16);
    ps += __shfl_xor(ps, 32);
    l = l * c + ps;

    // rescale accumulator: c per PV row (query hi*4+j) via bpermute
    float cc[4];
#pragma unroll
    for (int j = 0; j < 4; ++j) cc[j] = __shfl(c, hi * 4 + j);
#pragma unroll
    for (int dt = 0; dt < 4; ++dt)
#pragma unroll
      for (int j = 0; j < 4; ++j) po[dt][j] *= cc[j];

    // P^T -> P through LDS (wave-private, padded stride)
#pragma unroll
    for (int kr = 0; kr < 4; ++kr) {
      bf16x4 w4;
#pragma unroll
      for (int j = 0; j < 4; ++j) w4[j] = (bf16)sc[kr][j];
      *reinterpret_cast<bf16x4*>(pw + ln * LDP + kr * 16 + hi * 4) = w4;
    }
    bf16x8 pa0 = load8(pw + ln * LDP + hi * 8);
    bf16x8 pa1 = load8(pw + ln * LDP + 32 + hi * 8);

#pragma unroll
    for (int dt = 0; dt < 4; ++dt) {
      po[dt] = mfma16(pa0, bv0[dt], po[dt]);
      po[dt] = mfma16(pa1, bv1[dt], po[dt]);
    }
  }

  // epilogue: normalize, gate, store
  float lf[4];
#pragma unroll
  for (int j = 0; j < 4; ++j) lf[j] = __shfl(l, hi * 4 + j);
#pragma unroll
  for (int dt = 0; dt < 4; ++dt)
#pragma unroll
    for (int j = 0; j < 4; ++j) {
      int qq = qb + hi * 4 + j;
      int d  = dt * 16 + ln;
      float o  = po[dt][j] / lf[j];
      float gv = (float)qg[(size_t)qq * NQG + h * 128 + 64 + d];
      float sg = 1.0f / (1.0f + __expf(-gv));
      ctxg[(size_t)qq * D + h * 64 + d] = (bf16)(o * sg);
    }
}

__global__ __launch_bounds__(256) void attn(
    const bf16* __restrict__ qrot, const bf16* __restrict__ krot,
    const bf16* __restrict__ vt, const bf16* __restrict__ qg,
    bf16* __restrict__ ctxg)
{
  __shared__ __align__(16) bf16 Pl[4][16 * LDP];
  const int wave = threadIdx.x >> 6;
  const int lane = threadIdx.x & 63;
  const int ln = lane & 15, hi = lane >> 4;
  const int h  = blockIdx.x >> 4;   // 32 heads
  const int pr = blockIdx.x & 15;   // pair 0..15
  const int g  = h >> 2;            // GS = 4
  bf16* pw = &Pl[wave][0];

  attn_qtile(qrot, krot, vt, qg, ctxg, pw, h, g, pr * 64 + wave * 16, ln, hi);
  attn_qtile(qrot, krot, vt, qg, ctxg, pw, h, g, (31 - pr) * 64 + wave * 16, ln, hi);
}

// ---------------------------------------------------------------------------
// Output projection (unchanged; f32 output).
// ---------------------------------------------------------------------------
__global__ __launch_bounds__(256) void gemm_out(
    const bf16* __restrict__ A, const bf16* __restrict__ W,
    float* __restrict__ C)
{
  const int wave = threadIdx.x >> 6;
  const int lane = threadIdx.x & 63;
  const int ln = lane & 15, hi = lane >> 4;
  const int m0 = blockIdx.y * 256 + wave * 64;
  const int n0 = blockIdx.x * 64;

  f32x4 acc[4][4] = {};
  const bf16* ap = A + (size_t)(m0 + ln) * D + hi * 8;
  const bf16* bp = W + (size_t)(n0 + ln) * D + hi * 8;

  for (int k0 = 0; k0 < D; k0 += 32) {
    bf16x8 a[4], b[4];
#pragma unroll
    for (int i = 0; i < 4; ++i) {
      a[i] = load8(ap + i * 16 * D + k0);
      b[i] = load8(bp + i * 16 * D + k0);
    }
#pragma unroll
    for (int mi = 0; mi < 4; ++mi)
#pragma unroll
      for (int ni = 0; ni < 4; ++ni)
        acc[mi][ni] = mfma16(a[mi], b[ni], acc[mi][ni]);
  }

#pragma unroll
  for (int mi = 0; mi < 4; ++mi)
#pragma unroll
    for (int ni = 0; ni < 4; ++ni)
#pragma unroll
      for (int j = 0; j < 4; ++j) {
        int r = m0 + mi * 16 + hi * 4 + j;
        int c = n0 + ni * 16 + ln;
        C[(size_t)r * D + c] = acc[mi][ni][j];
      }
}

// ---------------------------------------------------------------------------
extern "C" void kernel_launch(void* const* d_in, const int* in_sizes, int n_in,
                              void* d_out, int out_size, void* d_ws, size_t ws_size,
                              hipStream_t stream) {
  const float* x    = (const float*)d_in[0];
  // d_in[1] = mask (bool) — causal triu(k=1), computed analytically
  const float* cosb = (const float*)d_in[2];
  const float* sinb = (const float*)d_in[3];
  const float* Wq   = (const float*)d_in[4];
  const float* Wk   = (const float*)d_in[5];
  const float* Wv   = (const float*)d_in[6];
  const float* Wo   = (const float*)d_in[7];
  const float* qw   = (const float*)d_in[8];
  const float* kw   = (const float*)d_in[9];

  char* ws = (char*)d_ws;
  bf16* xb   = (bf16*)(ws);                       //  8 MB
  bf16* Wqb  = (bf16*)(ws + ( 8u << 20));         // 16 MB
  bf16* Wkb  = (bf16*)(ws + (24u << 20));         //  2 MB
  bf16* Wvb  = (bf16*)(ws + (26u << 20));         //  2 MB
  bf16* Wob  = (bf16*)(ws + (28u << 20));         //  8 MB
  bf16* qg   = (bf16*)(ws + (36u << 20));         // 16 MB
  bf16* kpre = (bf16*)(ws + (52u << 20));         //  2 MB
  bf16* vt   = (bf16*)(ws + (54u << 20));         //  2 MB  [channel][s]
  bf16* qrot = (bf16*)(ws + (56u << 20));         //  8 MB  [h][s][d]
  bf16* krot = (bf16*)(ws + (64u << 20));         //  2 MB  [g][s][d]
  bf16* ctxg = (bf16*)(ws + (66u << 20));         //  8 MB
  float* out = (float*)d_out;

  cvt_f32_bf16<<<dim3(2048), 256, 0, stream>>>(x,  xb,  S * D);
  cvt_f32_bf16<<<dim3(4096), 256, 0, stream>>>(Wq, Wqb, NQG * D);
  cvt_f32_bf16<<<dim3(512),  256, 0, stream>>>(Wk, Wkb, NKV * D);
  cvt_f32_bf16<<<dim3(512),  256, 0, stream>>>(Wv, Wvb, NKV * D);
  cvt_f32_bf16<<<dim3(2048), 256, 0, stream>>>(Wo, Wob, D * D);

  gemm_qkv<<<dim3(80, 8), 256, 0, stream>>>(xb, Wqb, Wkb, Wvb, qg, kpre, vt);
  rmsrope<<<dim3(20480), 256, 0, stream>>>(qg, kpre, cosb, sinb, qw, kw, qrot, krot);
  attn<<<dim3(512), 256, 0, stream>>>(qrot, krot, vt, qg, ctxg);
  gemm_out<<<dim3(32, 8), 256, 0, stream>>>(ctxg, Wob, out);
}

// Round 4
// 234.215 us; speedup vs baseline: 2.2147x; 1.7615x over previous
//
#include <hip/hip_runtime.h>

typedef __bf16 bf16;
typedef __bf16 bf16x4 __attribute__((ext_vector_type(4)));
typedef __bf16 bf16x8 __attribute__((ext_vector_type(8)));
typedef float f32x4 __attribute__((ext_vector_type(4)));

#define DEV static __device__ __forceinline__

constexpr int S  = 2048;
constexpr int D  = 2048;
constexpr int H  = 32;
constexpr int G  = 8;
constexpr int HD = 64;
constexpr int NQG = 2 * H * HD;  // 4096
constexpr int NKV = G * HD;      // 512
constexpr int LDP = 72;          // padded LDS stride for attn P tile

DEV bf16x8 load8(const bf16* p) { return *reinterpret_cast<const bf16x8*>(p); }

DEV f32x4 mfma16(bf16x8 a, bf16x8 b, f32x4 c) {
  return __builtin_amdgcn_mfma_f32_16x16x32_bf16(a, b, c, 0, 0, 0);
}

DEV void gload_lds16(const bf16* g, bf16* l) {
  __builtin_amdgcn_global_load_lds(
      (const __attribute__((address_space(1))) void*)g,
      (__attribute__((address_space(3))) void*)l, 16, 0, 0);
}

// Stage a [ROWS][64] bf16 tile into LDS with chunk-XOR swizzle.
// LDS linear layout: 1KB blocks; lane l lands at block_base + l*16B.
// Linear slot (row r, 16B-slot s=l&7) is filled from source chunk c = s^(r&7),
// so a reader of logical chunk c reads slot c^(r&7). Source reads stay
// 128B-coalesced (8 lanes permute chunks within one 128B row segment).
template <int NISS>  // issues per wave: ROWS = NISS*32 (4 -> 128 rows, 2 -> 64)
DEV void stage_tile(bf16* lds, const bf16* src_row0, size_t ld, int k0, int tid) {
  const int w = tid >> 6, l = tid & 63;
#pragma unroll
  for (int i = 0; i < NISS; ++i) {
    int blk = w * NISS + i;            // 1KB LDS block
    int r = blk * 8 + (l >> 3);
    int c = (l & 7) ^ (r & 7);
    gload_lds16(src_row0 + (size_t)r * ld + k0 + c * 8, lds + blk * 512);
  }
}

// Read an 8-elem fragment (logical chunk) from a swizzled [*][64] LDS tile.
DEV bf16x8 fragr(const bf16* T, int row, int chunk) {
  return load8(T + row * 64 + (((chunk ^ (row & 7)) << 3)));
}

// ---------------------------------------------------------------------------
// f32 -> bf16 conversion.
// ---------------------------------------------------------------------------
__global__ __launch_bounds__(256) void cvt_f32_bf16(
    const float* __restrict__ in, bf16* __restrict__ out, int n)
{
  int i = (int)(blockIdx.x * 256u + threadIdx.x) * 8;
  if (i >= n) return;
  const float4* p = reinterpret_cast<const float4*>(in + i);
  float4 a = p[0], b = p[1];
  bf16x8 o;
  o[0] = (bf16)a.x; o[1] = (bf16)a.y; o[2] = (bf16)a.z; o[3] = (bf16)a.w;
  o[4] = (bf16)b.x; o[5] = (bf16)b.y; o[6] = (bf16)b.z; o[7] = (bf16)b.w;
  *reinterpret_cast<bf16x8*>(out + i) = o;
}

// ---------------------------------------------------------------------------
// Fused QKV projection, m97 structure: 128x128 tile, BK=64, LDS-staged.
// grid = (40, 16): bx<32 -> qg, 32..35 -> kpre, 36..39 -> vt (transposed).
// 4 waves (2x2), each 64x64 (acc 4x4).
// ---------------------------------------------------------------------------
__global__ __launch_bounds__(256, 3) void gemm_qkv(
    const bf16* __restrict__ X, const bf16* __restrict__ Wq,
    const bf16* __restrict__ Wk, const bf16* __restrict__ Wv,
    bf16* __restrict__ qg, bf16* __restrict__ kpre, bf16* __restrict__ vt)
{
  __shared__ __align__(16) bf16 As[128 * 64];
  __shared__ __align__(16) bf16 Bs[128 * 64];

  const int tid  = threadIdx.x;
  const int wave = tid >> 6;
  const int lane = tid & 63;
  const int ln = lane & 15, hi = lane >> 4;
  const int wm = wave >> 1, wn = wave & 1;
  const int m0 = blockIdx.y * 128;
  const int nt = blockIdx.x;

  const bf16* W; int n0;
  if (nt < 32)      { W = Wq; n0 = nt * 128; }
  else if (nt < 36) { W = Wk; n0 = (nt - 32) * 128; }
  else              { W = Wv; n0 = (nt - 36) * 128; }

  const bf16* arow = X + (size_t)m0 * D;
  const bf16* brow = W + (size_t)n0 * D;

  f32x4 acc[4][4] = {};

  for (int k0 = 0; k0 < D; k0 += 64) {
    __syncthreads();
    stage_tile<4>(As, arow, D, k0, tid);
    stage_tile<4>(Bs, brow, D, k0, tid);
    __syncthreads();
#pragma unroll
    for (int kk = 0; kk < 64; kk += 32) {
      bf16x8 a[4], b[4];
#pragma unroll
      for (int mi = 0; mi < 4; ++mi) a[mi] = fragr(As, wm * 64 + mi * 16 + ln, (kk >> 3) + hi);
#pragma unroll
      for (int ni = 0; ni < 4; ++ni) b[ni] = fragr(Bs, wn * 64 + ni * 16 + ln, (kk >> 3) + hi);
#pragma unroll
      for (int mi = 0; mi < 4; ++mi)
#pragma unroll
        for (int ni = 0; ni < 4; ++ni)
          acc[mi][ni] = mfma16(a[mi], b[ni], acc[mi][ni]);
    }
  }

  if (nt < 36) {
    bf16* C; int ldc;
    if (nt < 32) { C = qg; ldc = NQG; } else { C = kpre; ldc = NKV; }
#pragma unroll
    for (int mi = 0; mi < 4; ++mi)
#pragma unroll
      for (int ni = 0; ni < 4; ++ni)
#pragma unroll
        for (int j = 0; j < 4; ++j) {
          int r = m0 + wm * 64 + mi * 16 + hi * 4 + j;
          int c = n0 + wn * 64 + ni * 16 + ln;
          C[(size_t)r * ldc + c] = (bf16)acc[mi][ni][j];
        }
  } else {
    int nrel = (nt - 36) * 128;
#pragma unroll
    for (int mi = 0; mi < 4; ++mi)
#pragma unroll
      for (int ni = 0; ni < 4; ++ni)
#pragma unroll
        for (int j = 0; j < 4; ++j) {
          int r = m0 + wm * 64 + mi * 16 + hi * 4 + j;          // s
          int c = nrel + wn * 64 + ni * 16 + ln;                // channel
          vt[(size_t)c * S + r] = (bf16)acc[mi][ni][j];
        }
  }
}

// ---------------------------------------------------------------------------
// Output projection, same structure, 128x64 tile (512 blocks).
// 4 waves stacked on M: each 32x64 (acc 2x4). f32 output.
// ---------------------------------------------------------------------------
__global__ __launch_bounds__(256, 3) void gemm_out(
    const bf16* __restrict__ A, const bf16* __restrict__ W,
    float* __restrict__ C)
{
  __shared__ __align__(16) bf16 As[128 * 64];
  __shared__ __align__(16) bf16 Bs[64 * 64];

  const int tid  = threadIdx.x;
  const int wave = tid >> 6;
  const int lane = tid & 63;
  const int ln = lane & 15, hi = lane >> 4;
  const int m0 = blockIdx.y * 128;
  const int n0 = blockIdx.x * 64;

  const bf16* arow = A + (size_t)m0 * D;
  const bf16* brow = W + (size_t)n0 * D;

  f32x4 acc[2][4] = {};

  for (int k0 = 0; k0 < D; k0 += 64) {
    __syncthreads();
    stage_tile<4>(As, arow, D, k0, tid);
    stage_tile<2>(Bs, brow, D, k0, tid);
    __syncthreads();
#pragma unroll
    for (int kk = 0; kk < 64; kk += 32) {
      bf16x8 a[2], b[4];
#pragma unroll
      for (int mi = 0; mi < 2; ++mi) a[mi] = fragr(As, wave * 32 + mi * 16 + ln, (kk >> 3) + hi);
#pragma unroll
      for (int ni = 0; ni < 4; ++ni) b[ni] = fragr(Bs, ni * 16 + ln, (kk >> 3) + hi);
#pragma unroll
      for (int mi = 0; mi < 2; ++mi)
#pragma unroll
        for (int ni = 0; ni < 4; ++ni)
          acc[mi][ni] = mfma16(a[mi], b[ni], acc[mi][ni]);
    }
  }

#pragma unroll
  for (int mi = 0; mi < 2; ++mi)
#pragma unroll
    for (int ni = 0; ni < 4; ++ni)
#pragma unroll
      for (int j = 0; j < 4; ++j) {
        int r = m0 + wave * 32 + mi * 16 + hi * 4 + j;
        int c = n0 + ni * 16 + ln;
        C[(size_t)r * D + c] = acc[mi][ni][j];
      }
}

// ---------------------------------------------------------------------------
// RMSNorm + RoPE (unchanged).
// ---------------------------------------------------------------------------
__global__ __launch_bounds__(256) void rmsrope(
    const bf16* __restrict__ qg, const bf16* __restrict__ kpre,
    const float* __restrict__ cosb, const float* __restrict__ sinb,
    const float* __restrict__ qw, const float* __restrict__ kw,
    bf16* __restrict__ qrot, bf16* __restrict__ krot)
{
  int wid  = (int)((blockIdx.x * (unsigned)blockDim.x + threadIdx.x) >> 6);
  int lane = threadIdx.x & 63;
  int s  = wid & (S - 1);
  int hh = wid >> 11;  // 0..39

  float v, wgt;
  if (hh < H) { v = (float)qg[(size_t)s * NQG + hh * 128 + lane];        wgt = qw[lane]; }
  else        { v = (float)kpre[(size_t)s * NKV + (hh - H) * 64 + lane]; wgt = kw[lane]; }

  float ss = v * v;
#pragma unroll
  for (int m = 1; m < 64; m <<= 1) ss += __shfl_xor(ss, m);
  float xf = v * (1.0f / sqrtf(ss * (1.0f / 64.0f) + 1e-6f)) * (1.0f + wgt);

  float part = __shfl_xor(xf, 32);
  float rot  = (lane < 32) ? -part : part;
  float c  = cosb[(size_t)s * HD + lane];
  float sn = sinb[(size_t)s * HD + lane];
  bf16 outv = (bf16)(xf * c + rot * sn);

  if (hh < H) qrot[((size_t)hh * S + s) * HD + lane] = outv;
  else        krot[((size_t)(hh - H) * S + s) * HD + lane] = outv;
}

// ---------------------------------------------------------------------------
// Flash attention, swapped-QK^T formulation (unchanged from passing round).
// ---------------------------------------------------------------------------
DEV void attn_qtile(const bf16* __restrict__ qrot, const bf16* __restrict__ krot,
                    const bf16* __restrict__ vt, const bf16* __restrict__ qg,
                    bf16* __restrict__ ctxg, bf16* pw,
                    int h, int g, int qb, int ln, int hi)
{
  const float scale2 = 0.18033688011111204f;  // 0.125 * log2(e)

  const bf16* qbase = qrot + ((size_t)h * S + qb + ln) * HD + hi * 8;
  bf16x8 q0 = load8(qbase);
  bf16x8 q1 = load8(qbase + 32);

  f32x4 po[4] = {};
  float m = -INFINITY, l = 0.f;
  const int q = qb + ln;
  const int ntiles = (qb >> 6) + 1;

  for (int t = 0; t < ntiles; ++t) {
    const int key0 = t << 6;
    const bf16* kb = krot + ((size_t)g * S + key0) * HD;

    bf16x8 kf0[4], kf1[4];
#pragma unroll
    for (int kr = 0; kr < 4; ++kr) {
      kf0[kr] = load8(kb + (kr * 16 + ln) * HD + hi * 8);
      kf1[kr] = load8(kb + (kr * 16 + ln) * HD + 32 + hi * 8);
    }
    bf16x8 bv0[4], bv1[4];
#pragma unroll
    for (int dt = 0; dt < 4; ++dt) {
      const bf16* vb = vt + ((size_t)g * 64 + dt * 16 + ln) * S + key0 + hi * 8;
      bv0[dt] = load8(vb);
      bv1[dt] = load8(vb + 32);
    }

    f32x4 sc[4] = {};
#pragma unroll
    for (int kr = 0; kr < 4; ++kr) {
      sc[kr] = mfma16(kf0[kr], q0, sc[kr]);
      sc[kr] = mfma16(kf1[kr], q1, sc[kr]);
    }

    float pmax = -INFINITY;
#pragma unroll
    for (int kr = 0; kr < 4; ++kr)
#pragma unroll
      for (int j = 0; j < 4; ++j) {
        int key = key0 + kr * 16 + hi * 4 + j;
        float v = (key <= q) ? sc[kr][j] * scale2 : -INFINITY;
        sc[kr][j] = v;
        pmax = fmaxf(pmax, v);
      }
    pmax = fmaxf(pmax, __shfl_xor(pmax, 16));
    pmax = fmaxf(pmax, __shfl_xor(pmax, 32));
    float mn = fmaxf(m, pmax);
    float c = exp2f(m - mn);
    m = mn;

    float ps = 0.f;
#pragma unroll
    for (int kr = 0; kr < 4; ++kr)
#pragma unroll
      for (int j = 0; j < 4; ++j) {
        float e = exp2f(sc[kr][j] - mn);
        sc[kr][j] = e;
        ps += e;
      }
    ps += __shfl_xor(ps, 16);
    ps += __shfl_xor(ps, 32);
    l = l * c + ps;

    float cc[4];
#pragma unroll
    for (int j = 0; j < 4; ++j) cc[j] = __shfl(c, hi * 4 + j);
#pragma unroll
    for (int dt = 0; dt < 4; ++dt)
#pragma unroll
      for (int j = 0; j < 4; ++j) po[dt][j] *= cc[j];

#pragma unroll
    for (int kr = 0; kr < 4; ++kr) {
      bf16x4 w4;
#pragma unroll
      for (int j = 0; j < 4; ++j) w4[j] = (bf16)sc[kr][j];
      *reinterpret_cast<bf16x4*>(pw + ln * LDP + kr * 16 + hi * 4) = w4;
    }
    bf16x8 pa0 = load8(pw + ln * LDP + hi * 8);
    bf16x8 pa1 = load8(pw + ln * LDP + 32 + hi * 8);

#pragma unroll
    for (int dt = 0; dt < 4; ++dt) {
      po[dt] = mfma16(pa0, bv0[dt], po[dt]);
      po[dt] = mfma16(pa1, bv1[dt], po[dt]);
    }
  }

  float lf[4];
#pragma unroll
  for (int j = 0; j < 4; ++j) lf[j] = __shfl(l, hi * 4 + j);
#pragma unroll
  for (int dt = 0; dt < 4; ++dt)
#pragma unroll
    for (int j = 0; j < 4; ++j) {
      int qq = qb + hi * 4 + j;
      int d  = dt * 16 + ln;
      float o  = po[dt][j] / lf[j];
      float gv = (float)qg[(size_t)qq * NQG + h * 128 + 64 + d];
      float sg = 1.0f / (1.0f + __expf(-gv));
      ctxg[(size_t)qq * D + h * 64 + d] = (bf16)(o * sg);
    }
}

__global__ __launch_bounds__(256) void attn(
    const bf16* __restrict__ qrot, const bf16* __restrict__ krot,
    const bf16* __restrict__ vt, const bf16* __restrict__ qg,
    bf16* __restrict__ ctxg)
{
  __shared__ __align__(16) bf16 Pl[4][16 * LDP];
  const int wave = threadIdx.x >> 6;
  const int lane = threadIdx.x & 63;
  const int ln = lane & 15, hi = lane >> 4;
  const int h  = blockIdx.x >> 4;
  const int pr = blockIdx.x & 15;
  const int g  = h >> 2;
  bf16* pw = &Pl[wave][0];

  attn_qtile(qrot, krot, vt, qg, ctxg, pw, h, g, pr * 64 + wave * 16, ln, hi);
  attn_qtile(qrot, krot, vt, qg, ctxg, pw, h, g, (31 - pr) * 64 + wave * 16, ln, hi);
}

// ---------------------------------------------------------------------------
extern "C" void kernel_launch(void* const* d_in, const int* in_sizes, int n_in,
                              void* d_out, int out_size, void* d_ws, size_t ws_size,
                              hipStream_t stream) {
  const float* x    = (const float*)d_in[0];
  const float* cosb = (const float*)d_in[2];
  const float* sinb = (const float*)d_in[3];
  const float* Wq   = (const float*)d_in[4];
  const float* Wk   = (const float*)d_in[5];
  const float* Wv   = (const float*)d_in[6];
  const float* Wo   = (const float*)d_in[7];
  const float* qw   = (const float*)d_in[8];
  const float* kw   = (const float*)d_in[9];

  char* ws = (char*)d_ws;
  bf16* xb   = (bf16*)(ws);                       //  8 MB
  bf16* Wqb  = (bf16*)(ws + ( 8u << 20));         // 16 MB
  bf16* Wkb  = (bf16*)(ws + (24u << 20));         //  2 MB
  bf16* Wvb  = (bf16*)(ws + (26u << 20));         //  2 MB
  bf16* Wob  = (bf16*)(ws + (28u << 20));         //  8 MB
  bf16* qg   = (bf16*)(ws + (36u << 20));         // 16 MB
  bf16* kpre = (bf16*)(ws + (52u << 20));         //  2 MB
  bf16* vt   = (bf16*)(ws + (54u << 20));         //  2 MB  [channel][s]
  bf16* qrot = (bf16*)(ws + (56u << 20));         //  8 MB  [h][s][d]
  bf16* krot = (bf16*)(ws + (64u << 20));         //  2 MB  [g][s][d]
  bf16* ctxg = (bf16*)(ws + (66u << 20));         //  8 MB
  float* out = (float*)d_out;

  cvt_f32_bf16<<<dim3(2048), 256, 0, stream>>>(x,  xb,  S * D);
  cvt_f32_bf16<<<dim3(4096), 256, 0, stream>>>(Wq, Wqb, NQG * D);
  cvt_f32_bf16<<<dim3(512),  256, 0, stream>>>(Wk, Wkb, NKV * D);
  cvt_f32_bf16<<<dim3(512),  256, 0, stream>>>(Wv, Wvb, NKV * D);
  cvt_f32_bf16<<<dim3(2048), 256, 0, stream>>>(Wo, Wob, D * D);

  gemm_qkv<<<dim3(40, 16), 256, 0, stream>>>(xb, Wqb, Wkb, Wvb, qg, kpre, vt);
  rmsrope<<<dim3(20480), 256, 0, stream>>>(qg, kpre, cosb, sinb, qw, kw, qrot, krot);
  attn<<<dim3(512), 256, 0, stream>>>(qrot, krot, vt, qg, ctxg);
  gemm_out<<<dim3(32, 16), 256, 0, stream>>>(ctxg, Wob, out);
}

// Round 5
// 170.695 us; speedup vs baseline: 3.0388x; 1.3721x over previous
//
#include <hip/hip_runtime.h>

typedef __bf16 bf16;
typedef __bf16 bf16x4 __attribute__((ext_vector_type(4)));
typedef __bf16 bf16x8 __attribute__((ext_vector_type(8)));
typedef float f32x4 __attribute__((ext_vector_type(4)));

#define DEV static __device__ __forceinline__

constexpr int S  = 2048;
constexpr int D  = 2048;
constexpr int H  = 32;
constexpr int G  = 8;
constexpr int HD = 64;
constexpr int NQG = 2 * H * HD;  // 4096
constexpr int NKV = G * HD;      // 512
constexpr int LDP = 72;          // padded LDS stride for attn P tile

DEV bf16x8 load8(const bf16* p) { return *reinterpret_cast<const bf16x8*>(p); }

DEV f32x4 mfma16(bf16x8 a, bf16x8 b, f32x4 c) {
  return __builtin_amdgcn_mfma_f32_16x16x32_bf16(a, b, c, 0, 0, 0);
}

DEV void gload_lds16(const bf16* g, bf16* l) {
  __builtin_amdgcn_global_load_lds(
      (const __attribute__((address_space(1))) void*)g,
      (__attribute__((address_space(3))) void*)l, 16, 0, 0);
}

// Stage a [ROWS][64] bf16 tile into LDS with chunk-XOR swizzle.
// Linear LDS dest (wave-uniform base + lane*16B); source chunk pre-swizzled:
// slot s of row r holds source chunk s^(r&7). Reads stay 128B-coalesced.
template <int NISS>  // ROWS = NISS*32 (4 -> 128 rows, 2 -> 64 rows)
DEV void stage_tile(bf16* lds, const bf16* src_row0, size_t ld, int k0, int tid) {
  const int w = tid >> 6, l = tid & 63;
#pragma unroll
  for (int i = 0; i < NISS; ++i) {
    int blk = w * NISS + i;            // 1KB LDS block
    int r = blk * 8 + (l >> 3);
    int c = (l & 7) ^ (r & 7);
    gload_lds16(src_row0 + (size_t)r * ld + k0 + c * 8, lds + blk * 512);
  }
}

// Read an 8-elem fragment (logical chunk) from a swizzled [*][64] LDS tile.
DEV bf16x8 fragr(const bf16* T, int row, int chunk) {
  return load8(T + row * 64 + (((chunk ^ (row & 7)) << 3)));
}

// ---------------------------------------------------------------------------
// f32 -> bf16 conversion.
// ---------------------------------------------------------------------------
__global__ __launch_bounds__(256) void cvt_f32_bf16(
    const float* __restrict__ in, bf16* __restrict__ out, int n)
{
  int i = (int)(blockIdx.x * 256u + threadIdx.x) * 8;
  if (i >= n) return;
  const float4* p = reinterpret_cast<const float4*>(in + i);
  float4 a = p[0], b = p[1];
  bf16x8 o;
  o[0] = (bf16)a.x; o[1] = (bf16)a.y; o[2] = (bf16)a.z; o[3] = (bf16)a.w;
  o[4] = (bf16)b.x; o[5] = (bf16)b.y; o[6] = (bf16)b.z; o[7] = (bf16)b.w;
  *reinterpret_cast<bf16x8*>(out + i) = o;
}

// ---------------------------------------------------------------------------
// Fused QKV projection, m97 structure: 128x128 tile, BK=64, LDS-staged.
// ---------------------------------------------------------------------------
__global__ __launch_bounds__(256, 3) void gemm_qkv(
    const bf16* __restrict__ X, const bf16* __restrict__ Wq,
    const bf16* __restrict__ Wk, const bf16* __restrict__ Wv,
    bf16* __restrict__ qg, bf16* __restrict__ kpre, bf16* __restrict__ vt)
{
  __shared__ __align__(16) bf16 As[128 * 64];
  __shared__ __align__(16) bf16 Bs[128 * 64];

  const int tid  = threadIdx.x;
  const int wave = tid >> 6;
  const int lane = tid & 63;
  const int ln = lane & 15, hi = lane >> 4;
  const int wm = wave >> 1, wn = wave & 1;
  const int m0 = blockIdx.y * 128;
  const int nt = blockIdx.x;

  const bf16* W; int n0;
  if (nt < 32)      { W = Wq; n0 = nt * 128; }
  else if (nt < 36) { W = Wk; n0 = (nt - 32) * 128; }
  else              { W = Wv; n0 = (nt - 36) * 128; }

  const bf16* arow = X + (size_t)m0 * D;
  const bf16* brow = W + (size_t)n0 * D;

  f32x4 acc[4][4] = {};

  for (int k0 = 0; k0 < D; k0 += 64) {
    __syncthreads();
    stage_tile<4>(As, arow, D, k0, tid);
    stage_tile<4>(Bs, brow, D, k0, tid);
    __syncthreads();
#pragma unroll
    for (int kk = 0; kk < 64; kk += 32) {
      bf16x8 a[4], b[4];
#pragma unroll
      for (int mi = 0; mi < 4; ++mi) a[mi] = fragr(As, wm * 64 + mi * 16 + ln, (kk >> 3) + hi);
#pragma unroll
      for (int ni = 0; ni < 4; ++ni) b[ni] = fragr(Bs, wn * 64 + ni * 16 + ln, (kk >> 3) + hi);
#pragma unroll
      for (int mi = 0; mi < 4; ++mi)
#pragma unroll
        for (int ni = 0; ni < 4; ++ni)
          acc[mi][ni] = mfma16(a[mi], b[ni], acc[mi][ni]);
    }
  }

  if (nt < 36) {
    bf16* C; int ldc;
    if (nt < 32) { C = qg; ldc = NQG; } else { C = kpre; ldc = NKV; }
#pragma unroll
    for (int mi = 0; mi < 4; ++mi)
#pragma unroll
      for (int ni = 0; ni < 4; ++ni)
#pragma unroll
        for (int j = 0; j < 4; ++j) {
          int r = m0 + wm * 64 + mi * 16 + hi * 4 + j;
          int c = n0 + wn * 64 + ni * 16 + ln;
          C[(size_t)r * ldc + c] = (bf16)acc[mi][ni][j];
        }
  } else {
    int nrel = (nt - 36) * 128;
#pragma unroll
    for (int mi = 0; mi < 4; ++mi)
#pragma unroll
      for (int ni = 0; ni < 4; ++ni)
#pragma unroll
        for (int j = 0; j < 4; ++j) {
          int r = m0 + wm * 64 + mi * 16 + hi * 4 + j;          // s
          int c = nrel + wn * 64 + ni * 16 + ln;                // channel
          vt[(size_t)c * S + r] = (bf16)acc[mi][ni][j];
        }
  }
}

// ---------------------------------------------------------------------------
// Output projection, 128x64 tile. f32 output.
// ---------------------------------------------------------------------------
__global__ __launch_bounds__(256, 3) void gemm_out(
    const bf16* __restrict__ A, const bf16* __restrict__ W,
    float* __restrict__ C)
{
  __shared__ __align__(16) bf16 As[128 * 64];
  __shared__ __align__(16) bf16 Bs[64 * 64];

  const int tid  = threadIdx.x;
  const int wave = tid >> 6;
  const int lane = tid & 63;
  const int ln = lane & 15, hi = lane >> 4;
  const int m0 = blockIdx.y * 128;
  const int n0 = blockIdx.x * 64;

  const bf16* arow = A + (size_t)m0 * D;
  const bf16* brow = W + (size_t)n0 * D;

  f32x4 acc[2][4] = {};

  for (int k0 = 0; k0 < D; k0 += 64) {
    __syncthreads();
    stage_tile<4>(As, arow, D, k0, tid);
    stage_tile<2>(Bs, brow, D, k0, tid);
    __syncthreads();
#pragma unroll
    for (int kk = 0; kk < 64; kk += 32) {
      bf16x8 a[2], b[4];
#pragma unroll
      for (int mi = 0; mi < 2; ++mi) a[mi] = fragr(As, wave * 32 + mi * 16 + ln, (kk >> 3) + hi);
#pragma unroll
      for (int ni = 0; ni < 4; ++ni) b[ni] = fragr(Bs, ni * 16 + ln, (kk >> 3) + hi);
#pragma unroll
      for (int mi = 0; mi < 2; ++mi)
#pragma unroll
        for (int ni = 0; ni < 4; ++ni)
          acc[mi][ni] = mfma16(a[mi], b[ni], acc[mi][ni]);
    }
  }

#pragma unroll
  for (int mi = 0; mi < 2; ++mi)
#pragma unroll
    for (int ni = 0; ni < 4; ++ni)
#pragma unroll
      for (int j = 0; j < 4; ++j) {
        int r = m0 + wave * 32 + mi * 16 + hi * 4 + j;
        int c = n0 + ni * 16 + ln;
        C[(size_t)r * D + c] = acc[mi][ni][j];
      }
}

// ---------------------------------------------------------------------------
// RMSNorm + RoPE. Q output is PRE-SCALED by 0.125*log2(e) for the attn
// log2-domain softmax; K output unscaled.
// ---------------------------------------------------------------------------
__global__ __launch_bounds__(256) void rmsrope(
    const bf16* __restrict__ qg, const bf16* __restrict__ kpre,
    const float* __restrict__ cosb, const float* __restrict__ sinb,
    const float* __restrict__ qw, const float* __restrict__ kw,
    bf16* __restrict__ qrot, bf16* __restrict__ krot)
{
  int wid  = (int)((blockIdx.x * (unsigned)blockDim.x + threadIdx.x) >> 6);
  int lane = threadIdx.x & 63;
  int s  = wid & (S - 1);
  int hh = wid >> 11;  // 0..39

  float v, wgt;
  if (hh < H) { v = (float)qg[(size_t)s * NQG + hh * 128 + lane];        wgt = qw[lane]; }
  else        { v = (float)kpre[(size_t)s * NKV + (hh - H) * 64 + lane]; wgt = kw[lane]; }

  float ss = v * v;
#pragma unroll
  for (int m = 1; m < 64; m <<= 1) ss += __shfl_xor(ss, m);
  float xf = v * (1.0f / sqrtf(ss * (1.0f / 64.0f) + 1e-6f)) * (1.0f + wgt);

  float part = __shfl_xor(xf, 32);
  float rot  = (lane < 32) ? -part : part;
  float c  = cosb[(size_t)s * HD + lane];
  float sn = sinb[(size_t)s * HD + lane];
  float r  = xf * c + rot * sn;

  if (hh < H) {
    qrot[((size_t)hh * S + s) * HD + lane] = (bf16)(r * 0.18033688011111204f);
  } else {
    krot[((size_t)(hh - H) * S + s) * HD + lane] = (bf16)r;
  }
}

// ---------------------------------------------------------------------------
// Flash attention: swapped QK^T + block-shared double-buffered K/V LDS
// staging (global_load_lds, counted vmcnt) + defer-max online softmax.
// Block = (h, pr): phase A = q-chunk pr (pr+1 tiles), phase B = chunk 31-pr
// (32-pr tiles) -> uniform 33 staged tiles per block.
// ---------------------------------------------------------------------------
DEV void attn_phase(const bf16* __restrict__ qrot, const bf16* __restrict__ krow,
                    const bf16* __restrict__ vrow, const bf16* __restrict__ qg,
                    bf16* __restrict__ ctxg,
                    bf16* Kb0, bf16* Kb1, bf16* Vb0, bf16* Vb1, bf16* pw,
                    int h, int qchunk, int nt, int ln, int hi, int tid)
{
  const int qb = qchunk * 64 + (tid >> 6) * 16;
  const int q  = qb + ln;

  const bf16* qbase = qrot + ((size_t)h * S + qb + ln) * HD + hi * 8;
  bf16x8 q0 = load8(qbase);
  bf16x8 q1 = load8(qbase + 32);

  f32x4 po[4] = {};
  float m = -INFINITY, l = 0.f;

  __syncthreads();  // protect buf0 from previous phase's readers
  stage_tile<2>(Kb0, krow, 64, 0, tid);
  stage_tile<2>(Vb0, vrow, S, 0, tid);

  for (int t = 0; t < nt; ++t) {
    const bf16* Kb = (t & 1) ? Kb1 : Kb0;
    const bf16* Vb = (t & 1) ? Vb1 : Vb0;

    if (t + 1 < nt) {
      __syncthreads();  // everyone done reading buf[cur^1] (tile t-1)
      bf16* Kn = (t & 1) ? Kb0 : Kb1;
      bf16* Vn = (t & 1) ? Vb0 : Vb1;
      stage_tile<2>(Kn, krow + (size_t)(t + 1) * 64 * 64, 64, 0, tid);
      stage_tile<2>(Vn, vrow, S, (t + 1) * 64, tid);
      asm volatile("s_waitcnt vmcnt(4)" ::: "memory");
    } else {
      asm volatile("s_waitcnt vmcnt(0)" ::: "memory");
    }
    __syncthreads();  // buf[cur] fully populated for all waves

    bf16x8 kf0[4], kf1[4];
#pragma unroll
    for (int kr = 0; kr < 4; ++kr) {
      kf0[kr] = fragr(Kb, kr * 16 + ln, hi);
      kf1[kr] = fragr(Kb, kr * 16 + ln, hi + 4);
    }

    f32x4 sc[4] = {};
    __builtin_amdgcn_s_setprio(1);
#pragma unroll
    for (int kr = 0; kr < 4; ++kr) {
      sc[kr] = mfma16(kf0[kr], q0, sc[kr]);
      sc[kr] = mfma16(kf1[kr], q1, sc[kr]);
    }
    __builtin_amdgcn_s_setprio(0);

    float pmax = -INFINITY;
    if (t == nt - 1) {
      // diagonal tile: apply causal mask
      const int key0 = t << 6;
#pragma unroll
      for (int kr = 0; kr < 4; ++kr)
#pragma unroll
        for (int j = 0; j < 4; ++j) {
          int key = key0 + kr * 16 + hi * 4 + j;
          float v = (key <= q) ? sc[kr][j] : -INFINITY;
          sc[kr][j] = v;
          pmax = fmaxf(pmax, v);
        }
    } else {
#pragma unroll
      for (int kr = 0; kr < 4; ++kr)
#pragma unroll
        for (int j = 0; j < 4; ++j) pmax = fmaxf(pmax, sc[kr][j]);
    }
    pmax = fmaxf(pmax, __shfl_xor(pmax, 16));
    pmax = fmaxf(pmax, __shfl_xor(pmax, 32));

    // defer-max: rescale only when the running max grows by > 8 (log2 dom.)
    if (__any(pmax > m + 8.0f)) {
      float mn = fmaxf(m, pmax);
      float c  = exp2f(m - mn);
      l *= c;
      float cc[4];
#pragma unroll
      for (int j = 0; j < 4; ++j) cc[j] = __shfl(c, hi * 4 + j);
#pragma unroll
      for (int dt = 0; dt < 4; ++dt)
#pragma unroll
        for (int j = 0; j < 4; ++j) po[dt][j] *= cc[j];
      m = mn;
    }

    float ps = 0.f;
#pragma unroll
    for (int kr = 0; kr < 4; ++kr)
#pragma unroll
      for (int j = 0; j < 4; ++j) {
        float e = exp2f(sc[kr][j] - m);
        sc[kr][j] = e;
        ps += e;
      }
    ps += __shfl_xor(ps, 16);
    ps += __shfl_xor(ps, 32);
    l += ps;

    // P^T -> P through wave-private LDS
#pragma unroll
    for (int kr = 0; kr < 4; ++kr) {
      bf16x4 w4;
#pragma unroll
      for (int j = 0; j < 4; ++j) w4[j] = (bf16)sc[kr][j];
      *reinterpret_cast<bf16x4*>(pw + ln * LDP + kr * 16 + hi * 4) = w4;
    }
    bf16x8 pa0 = load8(pw + ln * LDP + hi * 8);
    bf16x8 pa1 = load8(pw + ln * LDP + 32 + hi * 8);

    bf16x8 bv0[4], bv1[4];
#pragma unroll
    for (int dt = 0; dt < 4; ++dt) {
      bv0[dt] = fragr(Vb, dt * 16 + ln, hi);
      bv1[dt] = fragr(Vb, dt * 16 + ln, hi + 4);
    }
    __builtin_amdgcn_s_setprio(1);
#pragma unroll
    for (int dt = 0; dt < 4; ++dt) {
      po[dt] = mfma16(pa0, bv0[dt], po[dt]);
      po[dt] = mfma16(pa1, bv1[dt], po[dt]);
    }
    __builtin_amdgcn_s_setprio(0);
  }

  // epilogue: normalize, gate, store
  float lf[4];
#pragma unroll
  for (int j = 0; j < 4; ++j) lf[j] = __shfl(l, hi * 4 + j);
#pragma unroll
  for (int dt = 0; dt < 4; ++dt)
#pragma unroll
    for (int j = 0; j < 4; ++j) {
      int qq = qb + hi * 4 + j;
      int d  = dt * 16 + ln;
      float o  = po[dt][j] / lf[j];
      float gv = (float)qg[(size_t)qq * NQG + h * 128 + 64 + d];
      float sg = 1.0f / (1.0f + __expf(-gv));
      ctxg[(size_t)qq * D + h * 64 + d] = (bf16)(o * sg);
    }
}

__global__ __launch_bounds__(256) void attn(
    const bf16* __restrict__ qrot, const bf16* __restrict__ krot,
    const bf16* __restrict__ vt, const bf16* __restrict__ qg,
    bf16* __restrict__ ctxg)
{
  __shared__ __align__(16) bf16 Kbuf[2][64 * 64];
  __shared__ __align__(16) bf16 Vbuf[2][64 * 64];
  __shared__ __align__(16) bf16 Pl[4][16 * LDP];

  const int tid  = threadIdx.x;
  const int wave = tid >> 6;
  const int lane = tid & 63;
  const int ln = lane & 15, hi = lane >> 4;
  const int h  = blockIdx.x >> 4;
  const int pr = blockIdx.x & 15;
  const int g  = h >> 2;
  bf16* pw = &Pl[wave][0];

  const bf16* krow = krot + (size_t)g * S * HD;   // [key][d], ld=64
  const bf16* vrow = vt + (size_t)g * 64 * S;     // [channel][s], ld=S

  attn_phase(qrot, krow, vrow, qg, ctxg,
             &Kbuf[0][0], &Kbuf[1][0], &Vbuf[0][0], &Vbuf[1][0], pw,
             h, pr, pr + 1, ln, hi, tid);
  attn_phase(qrot, krow, vrow, qg, ctxg,
             &Kbuf[0][0], &Kbuf[1][0], &Vbuf[0][0], &Vbuf[1][0], pw,
             h, 31 - pr, 32 - pr, ln, hi, tid);
}

// ---------------------------------------------------------------------------
extern "C" void kernel_launch(void* const* d_in, const int* in_sizes, int n_in,
                              void* d_out, int out_size, void* d_ws, size_t ws_size,
                              hipStream_t stream) {
  const float* x    = (const float*)d_in[0];
  const float* cosb = (const float*)d_in[2];
  const float* sinb = (const float*)d_in[3];
  const float* Wq   = (const float*)d_in[4];
  const float* Wk   = (const float*)d_in[5];
  const float* Wv   = (const float*)d_in[6];
  const float* Wo   = (const float*)d_in[7];
  const float* qw   = (const float*)d_in[8];
  const float* kw   = (const float*)d_in[9];

  char* ws = (char*)d_ws;
  bf16* xb   = (bf16*)(ws);                       //  8 MB
  bf16* Wqb  = (bf16*)(ws + ( 8u << 20));         // 16 MB
  bf16* Wkb  = (bf16*)(ws + (24u << 20));         //  2 MB
  bf16* Wvb  = (bf16*)(ws + (26u << 20));         //  2 MB
  bf16* Wob  = (bf16*)(ws + (28u << 20));         //  8 MB
  bf16* qg   = (bf16*)(ws + (36u << 20));         // 16 MB
  bf16* kpre = (bf16*)(ws + (52u << 20));         //  2 MB
  bf16* vt   = (bf16*)(ws + (54u << 20));         //  2 MB  [channel][s]
  bf16* qrot = (bf16*)(ws + (56u << 20));         //  8 MB  [h][s][d] (pre-scaled)
  bf16* krot = (bf16*)(ws + (64u << 20));         //  2 MB  [g][s][d]
  bf16* ctxg = (bf16*)(ws + (66u << 20));         //  8 MB
  float* out = (float*)d_out;

  cvt_f32_bf16<<<dim3(2048), 256, 0, stream>>>(x,  xb,  S * D);
  cvt_f32_bf16<<<dim3(4096), 256, 0, stream>>>(Wq, Wqb, NQG * D);
  cvt_f32_bf16<<<dim3(512),  256, 0, stream>>>(Wk, Wkb, NKV * D);
  cvt_f32_bf16<<<dim3(512),  256, 0, stream>>>(Wv, Wvb, NKV * D);
  cvt_f32_bf16<<<dim3(2048), 256, 0, stream>>>(Wo, Wob, D * D);

  gemm_qkv<<<dim3(40, 16), 256, 0, stream>>>(xb, Wqb, Wkb, Wvb, qg, kpre, vt);
  rmsrope<<<dim3(20480), 256, 0, stream>>>(qg, kpre, cosb, sinb, qw, kw, qrot, krot);
  attn<<<dim3(512), 256, 0, stream>>>(qrot, krot, vt, qg, ctxg);
  gemm_out<<<dim3(32, 16), 256, 0, stream>>>(ctxg, Wob, out);
}

// Round 6
// 158.391 us; speedup vs baseline: 3.2749x; 1.0777x over previous
//
#include <hip/hip_runtime.h>

typedef __bf16 bf16;
typedef __bf16 bf16x4 __attribute__((ext_vector_type(4)));
typedef __bf16 bf16x8 __attribute__((ext_vector_type(8)));
typedef float f32x4 __attribute__((ext_vector_type(4)));

#define DEV static __device__ __forceinline__

constexpr int S  = 2048;
constexpr int D  = 2048;
constexpr int H  = 32;
constexpr int G  = 8;
constexpr int HD = 64;
constexpr int NQG = 2 * H * HD;  // 4096
constexpr int NKV = G * HD;      // 512
constexpr int LDP = 72;          // padded LDS stride for attn P tile

DEV bf16x8 load8(const bf16* p) { return *reinterpret_cast<const bf16x8*>(p); }

DEV f32x4 mfma16(bf16x8 a, bf16x8 b, f32x4 c) {
  return __builtin_amdgcn_mfma_f32_16x16x32_bf16(a, b, c, 0, 0, 0);
}

DEV void gload_lds16(const bf16* g, bf16* l) {
  __builtin_amdgcn_global_load_lds(
      (const __attribute__((address_space(1))) void*)g,
      (__attribute__((address_space(3))) void*)l, 16, 0, 0);
}

// Stage a [ROWS][64] bf16 tile into LDS with chunk-XOR swizzle.
// Linear LDS dest (wave-uniform base + lane*16B); source chunk pre-swizzled:
// slot s of row r holds source chunk s^(r&7). Reads stay 128B-coalesced.
template <int NISS>  // ROWS = NISS*32 (4 -> 128 rows, 2 -> 64 rows)
DEV void stage_tile(bf16* lds, const bf16* src_row0, size_t ld, int k0, int tid) {
  const int w = tid >> 6, l = tid & 63;
#pragma unroll
  for (int i = 0; i < NISS; ++i) {
    int blk = w * NISS + i;            // 1KB LDS block
    int r = blk * 8 + (l >> 3);
    int c = (l & 7) ^ (r & 7);
    gload_lds16(src_row0 + (size_t)r * ld + k0 + c * 8, lds + blk * 512);
  }
}

// Read an 8-elem fragment (logical chunk) from a swizzled [*][64] LDS tile.
DEV bf16x8 fragr(const bf16* T, int row, int chunk) {
  return load8(T + row * 64 + (((chunk ^ (row & 7)) << 3)));
}

DEV float fexp2(float x) { return __builtin_amdgcn_exp2f(x); }
DEV float frcp(float x)  { return __builtin_amdgcn_rcpf(x); }

// ---------------------------------------------------------------------------
// f32 -> bf16 conversion.
// ---------------------------------------------------------------------------
__global__ __launch_bounds__(256) void cvt_f32_bf16(
    const float* __restrict__ in, bf16* __restrict__ out, int n)
{
  int i = (int)(blockIdx.x * 256u + threadIdx.x) * 8;
  if (i >= n) return;
  const float4* p = reinterpret_cast<const float4*>(in + i);
  float4 a = p[0], b = p[1];
  bf16x8 o;
  o[0] = (bf16)a.x; o[1] = (bf16)a.y; o[2] = (bf16)a.z; o[3] = (bf16)a.w;
  o[4] = (bf16)b.x; o[5] = (bf16)b.y; o[6] = (bf16)b.z; o[7] = (bf16)b.w;
  *reinterpret_cast<bf16x8*>(out + i) = o;
}

// ---------------------------------------------------------------------------
// Fused QKV projection, m97 structure: 128x128 tile, BK=64, LDS-staged.
// ---------------------------------------------------------------------------
__global__ __launch_bounds__(256, 3) void gemm_qkv(
    const bf16* __restrict__ X, const bf16* __restrict__ Wq,
    const bf16* __restrict__ Wk, const bf16* __restrict__ Wv,
    bf16* __restrict__ qg, bf16* __restrict__ kpre, bf16* __restrict__ vt)
{
  __shared__ __align__(16) bf16 As[128 * 64];
  __shared__ __align__(16) bf16 Bs[128 * 64];

  const int tid  = threadIdx.x;
  const int wave = tid >> 6;
  const int lane = tid & 63;
  const int ln = lane & 15, hi = lane >> 4;
  const int wm = wave >> 1, wn = wave & 1;
  const int m0 = blockIdx.y * 128;
  const int nt = blockIdx.x;

  const bf16* W; int n0;
  if (nt < 32)      { W = Wq; n0 = nt * 128; }
  else if (nt < 36) { W = Wk; n0 = (nt - 32) * 128; }
  else              { W = Wv; n0 = (nt - 36) * 128; }

  const bf16* arow = X + (size_t)m0 * D;
  const bf16* brow = W + (size_t)n0 * D;

  f32x4 acc[4][4] = {};

  for (int k0 = 0; k0 < D; k0 += 64) {
    __syncthreads();
    stage_tile<4>(As, arow, D, k0, tid);
    stage_tile<4>(Bs, brow, D, k0, tid);
    __syncthreads();
#pragma unroll
    for (int kk = 0; kk < 64; kk += 32) {
      bf16x8 a[4], b[4];
#pragma unroll
      for (int mi = 0; mi < 4; ++mi) a[mi] = fragr(As, wm * 64 + mi * 16 + ln, (kk >> 3) + hi);
#pragma unroll
      for (int ni = 0; ni < 4; ++ni) b[ni] = fragr(Bs, wn * 64 + ni * 16 + ln, (kk >> 3) + hi);
#pragma unroll
      for (int mi = 0; mi < 4; ++mi)
#pragma unroll
        for (int ni = 0; ni < 4; ++ni)
          acc[mi][ni] = mfma16(a[mi], b[ni], acc[mi][ni]);
    }
  }

  if (nt < 36) {
    bf16* C; int ldc;
    if (nt < 32) { C = qg; ldc = NQG; } else { C = kpre; ldc = NKV; }
#pragma unroll
    for (int mi = 0; mi < 4; ++mi)
#pragma unroll
      for (int ni = 0; ni < 4; ++ni)
#pragma unroll
        for (int j = 0; j < 4; ++j) {
          int r = m0 + wm * 64 + mi * 16 + hi * 4 + j;
          int c = n0 + wn * 64 + ni * 16 + ln;
          C[(size_t)r * ldc + c] = (bf16)acc[mi][ni][j];
        }
  } else {
    int nrel = (nt - 36) * 128;
#pragma unroll
    for (int mi = 0; mi < 4; ++mi)
#pragma unroll
      for (int ni = 0; ni < 4; ++ni)
#pragma unroll
        for (int j = 0; j < 4; ++j) {
          int r = m0 + wm * 64 + mi * 16 + hi * 4 + j;          // s
          int c = nrel + wn * 64 + ni * 16 + ln;                // channel
          vt[(size_t)c * S + r] = (bf16)acc[mi][ni][j];
        }
  }
}

// ---------------------------------------------------------------------------
// Output projection, 128x64 tile. f32 output.
// ---------------------------------------------------------------------------
__global__ __launch_bounds__(256, 3) void gemm_out(
    const bf16* __restrict__ A, const bf16* __restrict__ W,
    float* __restrict__ C)
{
  __shared__ __align__(16) bf16 As[128 * 64];
  __shared__ __align__(16) bf16 Bs[64 * 64];

  const int tid  = threadIdx.x;
  const int wave = tid >> 6;
  const int lane = tid & 63;
  const int ln = lane & 15, hi = lane >> 4;
  const int m0 = blockIdx.y * 128;
  const int n0 = blockIdx.x * 64;

  const bf16* arow = A + (size_t)m0 * D;
  const bf16* brow = W + (size_t)n0 * D;

  f32x4 acc[2][4] = {};

  for (int k0 = 0; k0 < D; k0 += 64) {
    __syncthreads();
    stage_tile<4>(As, arow, D, k0, tid);
    stage_tile<2>(Bs, brow, D, k0, tid);
    __syncthreads();
#pragma unroll
    for (int kk = 0; kk < 64; kk += 32) {
      bf16x8 a[2], b[4];
#pragma unroll
      for (int mi = 0; mi < 2; ++mi) a[mi] = fragr(As, wave * 32 + mi * 16 + ln, (kk >> 3) + hi);
#pragma unroll
      for (int ni = 0; ni < 4; ++ni) b[ni] = fragr(Bs, ni * 16 + ln, (kk >> 3) + hi);
#pragma unroll
      for (int mi = 0; mi < 2; ++mi)
#pragma unroll
        for (int ni = 0; ni < 4; ++ni)
          acc[mi][ni] = mfma16(a[mi], b[ni], acc[mi][ni]);
    }
  }

#pragma unroll
  for (int mi = 0; mi < 2; ++mi)
#pragma unroll
    for (int ni = 0; ni < 4; ++ni)
#pragma unroll
      for (int j = 0; j < 4; ++j) {
        int r = m0 + wave * 32 + mi * 16 + hi * 4 + j;
        int c = n0 + ni * 16 + ln;
        C[(size_t)r * D + c] = acc[mi][ni][j];
      }
}

// ---------------------------------------------------------------------------
// RMSNorm + RoPE. Q output PRE-SCALED by 0.125*log2(e); K unscaled.
// ---------------------------------------------------------------------------
__global__ __launch_bounds__(256) void rmsrope(
    const bf16* __restrict__ qg, const bf16* __restrict__ kpre,
    const float* __restrict__ cosb, const float* __restrict__ sinb,
    const float* __restrict__ qw, const float* __restrict__ kw,
    bf16* __restrict__ qrot, bf16* __restrict__ krot)
{
  int wid  = (int)((blockIdx.x * (unsigned)blockDim.x + threadIdx.x) >> 6);
  int lane = threadIdx.x & 63;
  int s  = wid & (S - 1);
  int hh = wid >> 11;  // 0..39

  float v, wgt;
  if (hh < H) { v = (float)qg[(size_t)s * NQG + hh * 128 + lane];        wgt = qw[lane]; }
  else        { v = (float)kpre[(size_t)s * NKV + (hh - H) * 64 + lane]; wgt = kw[lane]; }

  float ss = v * v;
#pragma unroll
  for (int m = 1; m < 64; m <<= 1) ss += __shfl_xor(ss, m);
  float xf = v * (1.0f / sqrtf(ss * (1.0f / 64.0f) + 1e-6f)) * (1.0f + wgt);

  float part = __shfl_xor(xf, 32);
  float rot  = (lane < 32) ? -part : part;
  float c  = cosb[(size_t)s * HD + lane];
  float sn = sinb[(size_t)s * HD + lane];
  float r  = xf * c + rot * sn;

  if (hh < H) {
    qrot[((size_t)hh * S + s) * HD + lane] = (bf16)(r * 0.18033688011111204f);
  } else {
    krot[((size_t)(hh - H) * S + s) * HD + lane] = (bf16)r;
  }
}

// ---------------------------------------------------------------------------
// Flash attention: swapped QK^T, block-shared double-buffered K/V staging
// with RAW s_barrier + manual vmcnt (the compiler's __syncthreads drains
// vmcnt(0) and defeats prefetch — this keeps the next tile's loads in
// flight under the current tile's compute; T3 minimal 2-phase schedule).
// ---------------------------------------------------------------------------
#define BARRIER() asm volatile("s_barrier" ::: "memory")
#define VMDRAIN() asm volatile("s_waitcnt vmcnt(0)" ::: "memory")

DEV void attn_phase(const bf16* __restrict__ qrot, const bf16* __restrict__ krow,
                    const bf16* __restrict__ vrow, const bf16* __restrict__ qg,
                    bf16* __restrict__ ctxg,
                    bf16* Kb0, bf16* Kb1, bf16* Vb0, bf16* Vb1, bf16* pw,
                    int h, int qchunk, int nt, int ln, int hi, int tid)
{
  const int qb = qchunk * 64 + (tid >> 6) * 16;
  const int q  = qb + ln;

  const bf16* qbase = qrot + ((size_t)h * S + qb + ln) * HD + hi * 8;
  bf16x8 q0 = load8(qbase);
  bf16x8 q1 = load8(qbase + 32);

  f32x4 po[4] = {};
  float m = -INFINITY, l = 0.f;

  // prologue: stage tile 0, drain once, sync
  stage_tile<2>(Kb0, krow, 64, 0, tid);
  stage_tile<2>(Vb0, vrow, S, 0, tid);
  VMDRAIN();
  BARRIER();

  int cur = 0;
  for (int t = 0; t < nt; ++t) {
    const bf16* Kb = cur ? Kb1 : Kb0;
    const bf16* Vb = cur ? Vb1 : Vb0;

    // issue next tile's loads; they complete during this tile's compute
    if (t + 1 < nt) {
      bf16* Kn = cur ? Kb0 : Kb1;
      bf16* Vn = cur ? Vb0 : Vb1;
      stage_tile<2>(Kn, krow + (size_t)(t + 1) * 64 * 64, 64, 0, tid);
      stage_tile<2>(Vn, vrow, S, (t + 1) * 64, tid);
    }

    bf16x8 kf0[4], kf1[4];
#pragma unroll
    for (int kr = 0; kr < 4; ++kr) {
      kf0[kr] = fragr(Kb, kr * 16 + ln, hi);
      kf1[kr] = fragr(Kb, kr * 16 + ln, hi + 4);
    }
    bf16x8 bv0[4], bv1[4];
#pragma unroll
    for (int dt = 0; dt < 4; ++dt) {
      bv0[dt] = fragr(Vb, dt * 16 + ln, hi);
      bv1[dt] = fragr(Vb, dt * 16 + ln, hi + 4);
    }

    f32x4 sc[4] = {};
    __builtin_amdgcn_s_setprio(1);
#pragma unroll
    for (int kr = 0; kr < 4; ++kr) {
      sc[kr] = mfma16(kf0[kr], q0, sc[kr]);
      sc[kr] = mfma16(kf1[kr], q1, sc[kr]);
    }
    __builtin_amdgcn_s_setprio(0);

    float pmax = -INFINITY;
    if (t == nt - 1) {
      const int key0 = t << 6;
#pragma unroll
      for (int kr = 0; kr < 4; ++kr)
#pragma unroll
        for (int j = 0; j < 4; ++j) {
          int key = key0 + kr * 16 + hi * 4 + j;
          float v = (key <= q) ? sc[kr][j] : -INFINITY;
          sc[kr][j] = v;
          pmax = fmaxf(pmax, v);
        }
    } else {
#pragma unroll
      for (int kr = 0; kr < 4; ++kr)
#pragma unroll
        for (int j = 0; j < 4; ++j) pmax = fmaxf(pmax, sc[kr][j]);
    }
    pmax = fmaxf(pmax, __shfl_xor(pmax, 16));
    pmax = fmaxf(pmax, __shfl_xor(pmax, 32));

    // defer-max: rescale only when the running max grows by > 8 (log2 dom.)
    if (__any(pmax > m + 8.0f)) {
      float mn = fmaxf(m, pmax);
      float c  = fexp2(m - mn);
      l *= c;
      float cc[4];
#pragma unroll
      for (int j = 0; j < 4; ++j) cc[j] = __shfl(c, hi * 4 + j);
#pragma unroll
      for (int dt = 0; dt < 4; ++dt)
#pragma unroll
        for (int j = 0; j < 4; ++j) po[dt][j] *= cc[j];
      m = mn;
    }

    float ps = 0.f;
#pragma unroll
    for (int kr = 0; kr < 4; ++kr)
#pragma unroll
      for (int j = 0; j < 4; ++j) {
        float e = fexp2(sc[kr][j] - m);
        sc[kr][j] = e;
        ps += e;
      }
    ps += __shfl_xor(ps, 16);
    ps += __shfl_xor(ps, 32);
    l += ps;

    // P^T -> P through wave-private LDS (cvt_pk packs 2 f32 -> 2 bf16)
#pragma unroll
    for (int kr = 0; kr < 4; ++kr) {
      unsigned w0, w1;
      asm("v_cvt_pk_bf16_f32 %0, %1, %2" : "=v"(w0) : "v"(sc[kr][0]), "v"(sc[kr][1]));
      asm("v_cvt_pk_bf16_f32 %0, %1, %2" : "=v"(w1) : "v"(sc[kr][2]), "v"(sc[kr][3]));
      uint2 w = {w0, w1};
      *reinterpret_cast<uint2*>(pw + ln * LDP + kr * 16 + hi * 4) = w;
    }
    bf16x8 pa0 = load8(pw + ln * LDP + hi * 8);
    bf16x8 pa1 = load8(pw + ln * LDP + 32 + hi * 8);

    __builtin_amdgcn_s_setprio(1);
#pragma unroll
    for (int dt = 0; dt < 4; ++dt) {
      po[dt] = mfma16(pa0, bv0[dt], po[dt]);
      po[dt] = mfma16(pa1, bv1[dt], po[dt]);
    }
    __builtin_amdgcn_s_setprio(0);

    VMDRAIN();   // next tile's loads had the whole compute to land
    BARRIER();   // all waves: buf[cur^1] ready, buf[cur] free to overwrite
    cur ^= 1;
  }

  // epilogue: normalize, gate, store
  float lf[4];
#pragma unroll
  for (int j = 0; j < 4; ++j) lf[j] = __shfl(l, hi * 4 + j);
#pragma unroll
  for (int dt = 0; dt < 4; ++dt)
#pragma unroll
    for (int j = 0; j < 4; ++j) {
      int qq = qb + hi * 4 + j;
      int d  = dt * 16 + ln;
      float o  = po[dt][j] * frcp(lf[j]);
      float gv = (float)qg[(size_t)qq * NQG + h * 128 + 64 + d];
      float sg = frcp(1.0f + fexp2(gv * -1.442695040888963f));
      ctxg[(size_t)qq * D + h * 64 + d] = (bf16)(o * sg);
    }
}

__global__ __launch_bounds__(256) void attn(
    const bf16* __restrict__ qrot, const bf16* __restrict__ krot,
    const bf16* __restrict__ vt, const bf16* __restrict__ qg,
    bf16* __restrict__ ctxg)
{
  __shared__ __align__(16) bf16 Kbuf[2][64 * 64];
  __shared__ __align__(16) bf16 Vbuf[2][64 * 64];
  __shared__ __align__(16) bf16 Pl[4][16 * LDP];

  const int tid  = threadIdx.x;
  const int lane = tid & 63;
  const int ln = lane & 15, hi = lane >> 4;

  // XCD-aware decode: blocks with bid%8 == x share KV group g = x
  // (512KB per group -> L2-resident per XCD).
  const int bid = blockIdx.x;
  const int g   = bid & 7;
  const int i   = bid >> 3;            // 0..63
  const int h   = g * 4 + (i & 3);
  const int pr  = i >> 2;              // 0..15
  bf16* pw = &Pl[tid >> 6][0];

  const bf16* krow = krot + (size_t)g * S * HD;   // [key][d], ld=64
  const bf16* vrow = vt + (size_t)g * 64 * S;     // [channel][s], ld=S

  attn_phase(qrot, krow, vrow, qg, ctxg,
             &Kbuf[0][0], &Kbuf[1][0], &Vbuf[0][0], &Vbuf[1][0], pw,
             h, pr, pr + 1, ln, hi, tid);
  attn_phase(qrot, krow, vrow, qg, ctxg,
             &Kbuf[0][0], &Kbuf[1][0], &Vbuf[0][0], &Vbuf[1][0], pw,
             h, 31 - pr, 32 - pr, ln, hi, tid);
}

// ---------------------------------------------------------------------------
extern "C" void kernel_launch(void* const* d_in, const int* in_sizes, int n_in,
                              void* d_out, int out_size, void* d_ws, size_t ws_size,
                              hipStream_t stream) {
  const float* x    = (const float*)d_in[0];
  const float* cosb = (const float*)d_in[2];
  const float* sinb = (const float*)d_in[3];
  const float* Wq   = (const float*)d_in[4];
  const float* Wk   = (const float*)d_in[5];
  const float* Wv   = (const float*)d_in[6];
  const float* Wo   = (const float*)d_in[7];
  const float* qw   = (const float*)d_in[8];
  const float* kw   = (const float*)d_in[9];

  char* ws = (char*)d_ws;
  bf16* xb   = (bf16*)(ws);                       //  8 MB
  bf16* Wqb  = (bf16*)(ws + ( 8u << 20));         // 16 MB
  bf16* Wkb  = (bf16*)(ws + (24u << 20));         //  2 MB
  bf16* Wvb  = (bf16*)(ws + (26u << 20));         //  2 MB
  bf16* Wob  = (bf16*)(ws + (28u << 20));         //  8 MB
  bf16* qg   = (bf16*)(ws + (36u << 20));         // 16 MB
  bf16* kpre = (bf16*)(ws + (52u << 20));         //  2 MB
  bf16* vt   = (bf16*)(ws + (54u << 20));         //  2 MB  [channel][s]
  bf16* qrot = (bf16*)(ws + (56u << 20));         //  8 MB  [h][s][d] (pre-scaled)
  bf16* krot = (bf16*)(ws + (64u << 20));         //  2 MB  [g][s][d]
  bf16* ctxg = (bf16*)(ws + (66u << 20));         //  8 MB
  float* out = (float*)d_out;

  cvt_f32_bf16<<<dim3(2048), 256, 0, stream>>>(x,  xb,  S * D);
  cvt_f32_bf16<<<dim3(4096), 256, 0, stream>>>(Wq, Wqb, NQG * D);
  cvt_f32_bf16<<<dim3(512),  256, 0, stream>>>(Wk, Wkb, NKV * D);
  cvt_f32_bf16<<<dim3(512),  256, 0, stream>>>(Wv, Wvb, NKV * D);
  cvt_f32_bf16<<<dim3(2048), 256, 0, stream>>>(Wo, Wob, D * D);

  gemm_qkv<<<dim3(40, 16), 256, 0, stream>>>(xb, Wqb, Wkb, Wvb, qg, kpre, vt);
  rmsrope<<<dim3(20480), 256, 0, stream>>>(qg, kpre, cosb, sinb, qw, kw, qrot, krot);
  attn<<<dim3(512), 256, 0, stream>>>(qrot, krot, vt, qg, ctxg);
  gemm_out<<<dim3(32, 16), 256, 0, stream>>>(ctxg, Wob, out);
}

// Round 7
// 158.372 us; speedup vs baseline: 3.2752x; 1.0001x over previous
//
#include <hip/hip_runtime.h>

typedef __bf16 bf16;
typedef __bf16 bf16x4 __attribute__((ext_vector_type(4)));
typedef __bf16 bf16x8 __attribute__((ext_vector_type(8)));
typedef float f32x4 __attribute__((ext_vector_type(4)));

#define DEV static __device__ __forceinline__

constexpr int S  = 2048;
constexpr int D  = 2048;
constexpr int H  = 32;
constexpr int G  = 8;
constexpr int HD = 64;
constexpr int NQG = 2 * H * HD;  // 4096
constexpr int NKV = G * HD;      // 512
constexpr int LDP = 72;          // padded LDS stride for attn P tile

DEV bf16x8 load8(const bf16* p) { return *reinterpret_cast<const bf16x8*>(p); }

DEV f32x4 mfma16(bf16x8 a, bf16x8 b, f32x4 c) {
  return __builtin_amdgcn_mfma_f32_16x16x32_bf16(a, b, c, 0, 0, 0);
}

DEV void gload_lds16(const bf16* g, bf16* l) {
  __builtin_amdgcn_global_load_lds(
      (const __attribute__((address_space(1))) void*)g,
      (__attribute__((address_space(3))) void*)l, 16, 0, 0);
}

// Stage a [ROWS][64] bf16 tile into LDS with chunk-XOR swizzle.
// Linear LDS dest (wave-uniform base + lane*16B); source chunk pre-swizzled:
// slot s of row r holds source chunk s^(r&7). Reads stay 128B-coalesced.
template <int NISS>  // ROWS = NISS*32 (4 -> 128 rows, 2 -> 64 rows)
DEV void stage_tile(bf16* lds, const bf16* src_row0, size_t ld, int k0, int tid) {
  const int w = tid >> 6, l = tid & 63;
#pragma unroll
  for (int i = 0; i < NISS; ++i) {
    int blk = w * NISS + i;            // 1KB LDS block
    int r = blk * 8 + (l >> 3);
    int c = (l & 7) ^ (r & 7);
    gload_lds16(src_row0 + (size_t)r * ld + k0 + c * 8, lds + blk * 512);
  }
}

// Read an 8-elem fragment (logical chunk) from a swizzled [*][64] LDS tile.
DEV bf16x8 fragr(const bf16* T, int row, int chunk) {
  return load8(T + row * 64 + (((chunk ^ (row & 7)) << 3)));
}

DEV float fexp2(float x) { return __builtin_amdgcn_exp2f(x); }
DEV float frcp(float x)  { return __builtin_amdgcn_rcpf(x); }

// ---------------------------------------------------------------------------
// f32 -> bf16 conversion.
// ---------------------------------------------------------------------------
__global__ __launch_bounds__(256) void cvt_f32_bf16(
    const float* __restrict__ in, bf16* __restrict__ out, int n)
{
  int i = (int)(blockIdx.x * 256u + threadIdx.x) * 8;
  if (i >= n) return;
  const float4* p = reinterpret_cast<const float4*>(in + i);
  float4 a = p[0], b = p[1];
  bf16x8 o;
  o[0] = (bf16)a.x; o[1] = (bf16)a.y; o[2] = (bf16)a.z; o[3] = (bf16)a.w;
  o[4] = (bf16)b.x; o[5] = (bf16)b.y; o[6] = (bf16)b.z; o[7] = (bf16)b.w;
  *reinterpret_cast<bf16x8*>(out + i) = o;
}

// ---------------------------------------------------------------------------
// Fused QKV projection, m97 structure: 128x128 tile, BK=64, LDS-staged.
// ---------------------------------------------------------------------------
__global__ __launch_bounds__(256, 3) void gemm_qkv(
    const bf16* __restrict__ X, const bf16* __restrict__ Wq,
    const bf16* __restrict__ Wk, const bf16* __restrict__ Wv,
    bf16* __restrict__ qg, bf16* __restrict__ kpre, bf16* __restrict__ vt)
{
  __shared__ __align__(16) bf16 As[128 * 64];
  __shared__ __align__(16) bf16 Bs[128 * 64];

  const int tid  = threadIdx.x;
  const int wave = tid >> 6;
  const int lane = tid & 63;
  const int ln = lane & 15, hi = lane >> 4;
  const int wm = wave >> 1, wn = wave & 1;
  const int m0 = blockIdx.y * 128;
  const int nt = blockIdx.x;

  const bf16* W; int n0;
  if (nt < 32)      { W = Wq; n0 = nt * 128; }
  else if (nt < 36) { W = Wk; n0 = (nt - 32) * 128; }
  else              { W = Wv; n0 = (nt - 36) * 128; }

  const bf16* arow = X + (size_t)m0 * D;
  const bf16* brow = W + (size_t)n0 * D;

  f32x4 acc[4][4] = {};

  for (int k0 = 0; k0 < D; k0 += 64) {
    __syncthreads();
    stage_tile<4>(As, arow, D, k0, tid);
    stage_tile<4>(Bs, brow, D, k0, tid);
    __syncthreads();
#pragma unroll
    for (int kk = 0; kk < 64; kk += 32) {
      bf16x8 a[4], b[4];
#pragma unroll
      for (int mi = 0; mi < 4; ++mi) a[mi] = fragr(As, wm * 64 + mi * 16 + ln, (kk >> 3) + hi);
#pragma unroll
      for (int ni = 0; ni < 4; ++ni) b[ni] = fragr(Bs, wn * 64 + ni * 16 + ln, (kk >> 3) + hi);
#pragma unroll
      for (int mi = 0; mi < 4; ++mi)
#pragma unroll
        for (int ni = 0; ni < 4; ++ni)
          acc[mi][ni] = mfma16(a[mi], b[ni], acc[mi][ni]);
    }
  }

  if (nt < 36) {
    bf16* C; int ldc;
    if (nt < 32) { C = qg; ldc = NQG; } else { C = kpre; ldc = NKV; }
#pragma unroll
    for (int mi = 0; mi < 4; ++mi)
#pragma unroll
      for (int ni = 0; ni < 4; ++ni)
#pragma unroll
        for (int j = 0; j < 4; ++j) {
          int r = m0 + wm * 64 + mi * 16 + hi * 4 + j;
          int c = n0 + wn * 64 + ni * 16 + ln;
          C[(size_t)r * ldc + c] = (bf16)acc[mi][ni][j];
        }
  } else {
    int nrel = (nt - 36) * 128;
#pragma unroll
    for (int mi = 0; mi < 4; ++mi)
#pragma unroll
      for (int ni = 0; ni < 4; ++ni)
#pragma unroll
        for (int j = 0; j < 4; ++j) {
          int r = m0 + wm * 64 + mi * 16 + hi * 4 + j;          // s
          int c = nrel + wn * 64 + ni * 16 + ln;                // channel
          vt[(size_t)c * S + r] = (bf16)acc[mi][ni][j];
        }
  }
}

// ---------------------------------------------------------------------------
// Output projection, 128x64 tile. f32 output.
// ---------------------------------------------------------------------------
__global__ __launch_bounds__(256, 3) void gemm_out(
    const bf16* __restrict__ A, const bf16* __restrict__ W,
    float* __restrict__ C)
{
  __shared__ __align__(16) bf16 As[128 * 64];
  __shared__ __align__(16) bf16 Bs[64 * 64];

  const int tid  = threadIdx.x;
  const int wave = tid >> 6;
  const int lane = tid & 63;
  const int ln = lane & 15, hi = lane >> 4;
  const int m0 = blockIdx.y * 128;
  const int n0 = blockIdx.x * 64;

  const bf16* arow = A + (size_t)m0 * D;
  const bf16* brow = W + (size_t)n0 * D;

  f32x4 acc[2][4] = {};

  for (int k0 = 0; k0 < D; k0 += 64) {
    __syncthreads();
    stage_tile<4>(As, arow, D, k0, tid);
    stage_tile<2>(Bs, brow, D, k0, tid);
    __syncthreads();
#pragma unroll
    for (int kk = 0; kk < 64; kk += 32) {
      bf16x8 a[2], b[4];
#pragma unroll
      for (int mi = 0; mi < 2; ++mi) a[mi] = fragr(As, wave * 32 + mi * 16 + ln, (kk >> 3) + hi);
#pragma unroll
      for (int ni = 0; ni < 4; ++ni) b[ni] = fragr(Bs, ni * 16 + ln, (kk >> 3) + hi);
#pragma unroll
      for (int mi = 0; mi < 2; ++mi)
#pragma unroll
        for (int ni = 0; ni < 4; ++ni)
          acc[mi][ni] = mfma16(a[mi], b[ni], acc[mi][ni]);
    }
  }

#pragma unroll
  for (int mi = 0; mi < 2; ++mi)
#pragma unroll
    for (int ni = 0; ni < 4; ++ni)
#pragma unroll
      for (int j = 0; j < 4; ++j) {
        int r = m0 + wave * 32 + mi * 16 + hi * 4 + j;
        int c = n0 + ni * 16 + ln;
        C[(size_t)r * D + c] = acc[mi][ni][j];
      }
}

// ---------------------------------------------------------------------------
// RMSNorm + RoPE. Q output PRE-SCALED by 0.125*log2(e); K unscaled.
// ---------------------------------------------------------------------------
__global__ __launch_bounds__(256) void rmsrope(
    const bf16* __restrict__ qg, const bf16* __restrict__ kpre,
    const float* __restrict__ cosb, const float* __restrict__ sinb,
    const float* __restrict__ qw, const float* __restrict__ kw,
    bf16* __restrict__ qrot, bf16* __restrict__ krot)
{
  int wid  = (int)((blockIdx.x * (unsigned)blockDim.x + threadIdx.x) >> 6);
  int lane = threadIdx.x & 63;
  int s  = wid & (S - 1);
  int hh = wid >> 11;  // 0..39

  float v, wgt;
  if (hh < H) { v = (float)qg[(size_t)s * NQG + hh * 128 + lane];        wgt = qw[lane]; }
  else        { v = (float)kpre[(size_t)s * NKV + (hh - H) * 64 + lane]; wgt = kw[lane]; }

  float ss = v * v;
#pragma unroll
  for (int m = 1; m < 64; m <<= 1) ss += __shfl_xor(ss, m);
  float xf = v * (1.0f / sqrtf(ss * (1.0f / 64.0f) + 1e-6f)) * (1.0f + wgt);

  float part = __shfl_xor(xf, 32);
  float rot  = (lane < 32) ? -part : part;
  float c  = cosb[(size_t)s * HD + lane];
  float sn = sinb[(size_t)s * HD + lane];
  float r  = xf * c + rot * sn;

  if (hh < H) {
    qrot[((size_t)hh * S + s) * HD + lane] = (bf16)(r * 0.18033688011111204f);
  } else {
    krot[((size_t)(hh - H) * S + s) * HD + lane] = (bf16)r;
  }
}

// ---------------------------------------------------------------------------
// Flash attention: swapped QK^T, block-shared double-buffered K/V staging
// with RAW s_barrier + manual vmcnt (the compiler's __syncthreads drains
// vmcnt(0) and defeats prefetch — this keeps the next tile's loads in
// flight under the current tile's compute; T3 minimal 2-phase schedule).
// ---------------------------------------------------------------------------
#define BARRIER() asm volatile("s_barrier" ::: "memory")
#define VMDRAIN() asm volatile("s_waitcnt vmcnt(0)" ::: "memory")

DEV void attn_phase(const bf16* __restrict__ qrot, const bf16* __restrict__ krow,
                    const bf16* __restrict__ vrow, const bf16* __restrict__ qg,
                    bf16* __restrict__ ctxg,
                    bf16* Kb0, bf16* Kb1, bf16* Vb0, bf16* Vb1, bf16* pw,
                    int h, int qchunk, int nt, int ln, int hi, int tid)
{
  const int qb = qchunk * 64 + (tid >> 6) * 16;
  const int q  = qb + ln;

  const bf16* qbase = qrot + ((size_t)h * S + qb + ln) * HD + hi * 8;
  bf16x8 q0 = load8(qbase);
  bf16x8 q1 = load8(qbase + 32);

  f32x4 po[4] = {};
  float m = -INFINITY, l = 0.f;

  // prologue: stage tile 0, drain once, sync
  stage_tile<2>(Kb0, krow, 64, 0, tid);
  stage_tile<2>(Vb0, vrow, S, 0, tid);
  VMDRAIN();
  BARRIER();

  int cur = 0;
  for (int t = 0; t < nt; ++t) {
    const bf16* Kb = cur ? Kb1 : Kb0;
    const bf16* Vb = cur ? Vb1 : Vb0;

    // issue next tile's loads; they complete during this tile's compute
    if (t + 1 < nt) {
      bf16* Kn = cur ? Kb0 : Kb1;
      bf16* Vn = cur ? Vb0 : Vb1;
      stage_tile<2>(Kn, krow + (size_t)(t + 1) * 64 * 64, 64, 0, tid);
      stage_tile<2>(Vn, vrow, S, (t + 1) * 64, tid);
    }

    bf16x8 kf0[4], kf1[4];
#pragma unroll
    for (int kr = 0; kr < 4; ++kr) {
      kf0[kr] = fragr(Kb, kr * 16 + ln, hi);
      kf1[kr] = fragr(Kb, kr * 16 + ln, hi + 4);
    }
    bf16x8 bv0[4], bv1[4];
#pragma unroll
    for (int dt = 0; dt < 4; ++dt) {
      bv0[dt] = fragr(Vb, dt * 16 + ln, hi);
      bv1[dt] = fragr(Vb, dt * 16 + ln, hi + 4);
    }

    f32x4 sc[4] = {};
    __builtin_amdgcn_s_setprio(1);
#pragma unroll
    for (int kr = 0; kr < 4; ++kr) {
      sc[kr] = mfma16(kf0[kr], q0, sc[kr]);
      sc[kr] = mfma16(kf1[kr], q1, sc[kr]);
    }
    __builtin_amdgcn_s_setprio(0);

    float pmax = -INFINITY;
    if (t == nt - 1) {
      const int key0 = t << 6;
#pragma unroll
      for (int kr = 0; kr < 4; ++kr)
#pragma unroll
        for (int j = 0; j < 4; ++j) {
          int key = key0 + kr * 16 + hi * 4 + j;
          float v = (key <= q) ? sc[kr][j] : -INFINITY;
          sc[kr][j] = v;
          pmax = fmaxf(pmax, v);
        }
    } else {
#pragma unroll
      for (int kr = 0; kr < 4; ++kr)
#pragma unroll
        for (int j = 0; j < 4; ++j) pmax = fmaxf(pmax, sc[kr][j]);
    }
    pmax = fmaxf(pmax, __shfl_xor(pmax, 16));
    pmax = fmaxf(pmax, __shfl_xor(pmax, 32));

    // defer-max: rescale only when the running max grows by > 8 (log2 dom.)
    if (__any(pmax > m + 8.0f)) {
      float mn = fmaxf(m, pmax);
      float c  = fexp2(m - mn);
      l *= c;
      float cc[4];
#pragma unroll
      for (int j = 0; j < 4; ++j) cc[j] = __shfl(c, hi * 4 + j);
#pragma unroll
      for (int dt = 0; dt < 4; ++dt)
#pragma unroll
        for (int j = 0; j < 4; ++j) po[dt][j] *= cc[j];
      m = mn;
    }

    float ps = 0.f;
#pragma unroll
    for (int kr = 0; kr < 4; ++kr)
#pragma unroll
      for (int j = 0; j < 4; ++j) {
        float e = fexp2(sc[kr][j] - m);
        sc[kr][j] = e;
        ps += e;
      }
    ps += __shfl_xor(ps, 16);
    ps += __shfl_xor(ps, 32);
    l += ps;

    // P^T -> P through wave-private LDS (cvt_pk packs 2 f32 -> 2 bf16)
#pragma unroll
    for (int kr = 0; kr < 4; ++kr) {
      unsigned w0, w1;
      asm("v_cvt_pk_bf16_f32 %0, %1, %2" : "=v"(w0) : "v"(sc[kr][0]), "v"(sc[kr][1]));
      asm("v_cvt_pk_bf16_f32 %0, %1, %2" : "=v"(w1) : "v"(sc[kr][2]), "v"(sc[kr][3]));
      uint2 w = {w0, w1};
      *reinterpret_cast<uint2*>(pw + ln * LDP + kr * 16 + hi * 4) = w;
    }
    bf16x8 pa0 = load8(pw + ln * LDP + hi * 8);
    bf16x8 pa1 = load8(pw + ln * LDP + 32 + hi * 8);

    __builtin_amdgcn_s_setprio(1);
#pragma unroll
    for (int dt = 0; dt < 4; ++dt) {
      po[dt] = mfma16(pa0, bv0[dt], po[dt]);
      po[dt] = mfma16(pa1, bv1[dt], po[dt]);
    }
    __builtin_amdgcn_s_setprio(0);

    VMDRAIN();   // next tile's loads had the whole compute to land
    BARRIER();   // all waves: buf[cur^1] ready, buf[cur] free to overwrite
    cur ^= 1;
  }

  // epilogue: normalize, gate, store
  float lf[4];
#pragma unroll
  for (int j = 0; j < 4; ++j) lf[j] = __shfl(l, hi * 4 + j);
#pragma unroll
  for (int dt = 0; dt < 4; ++dt)
#pragma unroll
    for (int j = 0; j < 4; ++j) {
      int qq = qb + hi * 4 + j;
      int d  = dt * 16 + ln;
      float o  = po[dt][j] * frcp(lf[j]);
      float gv = (float)qg[(size_t)qq * NQG + h * 128 + 64 + d];
      float sg = frcp(1.0f + fexp2(gv * -1.442695040888963f));
      ctxg[(size_t)qq * D + h * 64 + d] = (bf16)(o * sg);
    }
}

__global__ __launch_bounds__(256) void attn(
    const bf16* __restrict__ qrot, const bf16* __restrict__ krot,
    const bf16* __restrict__ vt, const bf16* __restrict__ qg,
    bf16* __restrict__ ctxg)
{
  __shared__ __align__(16) bf16 Kbuf[2][64 * 64];
  __shared__ __align__(16) bf16 Vbuf[2][64 * 64];
  __shared__ __align__(16) bf16 Pl[4][16 * LDP];

  const int tid  = threadIdx.x;
  const int lane = tid & 63;
  const int ln = lane & 15, hi = lane >> 4;

  // XCD-aware decode: blocks with bid%8 == x share KV group g = x
  // (512KB per group -> L2-resident per XCD).
  const int bid = blockIdx.x;
  const int g   = bid & 7;
  const int i   = bid >> 3;            // 0..63
  const int h   = g * 4 + (i & 3);
  const int pr  = i >> 2;              // 0..15
  bf16* pw = &Pl[tid >> 6][0];

  const bf16* krow = krot + (size_t)g * S * HD;   // [key][d], ld=64
  const bf16* vrow = vt + (size_t)g * 64 * S;     // [channel][s], ld=S

  attn_phase(qrot, krow, vrow, qg, ctxg,
             &Kbuf[0][0], &Kbuf[1][0], &Vbuf[0][0], &Vbuf[1][0], pw,
             h, pr, pr + 1, ln, hi, tid);
  attn_phase(qrot, krow, vrow, qg, ctxg,
             &Kbuf[0][0], &Kbuf[1][0], &Vbuf[0][0], &Vbuf[1][0], pw,
             h, 31 - pr, 32 - pr, ln, hi, tid);
}

// ---------------------------------------------------------------------------
extern "C" void kernel_launch(void* const* d_in, const int* in_sizes, int n_in,
                              void* d_out, int out_size, void* d_ws, size_t ws_size,
                              hipStream_t stream) {
  const float* x    = (const float*)d_in[0];
  const float* cosb = (const float*)d_in[2];
  const float* sinb = (const float*)d_in[3];
  const float* Wq   = (const float*)d_in[4];
  const float* Wk   = (const float*)d_in[5];
  const float* Wv   = (const float*)d_in[6];
  const float* Wo   = (const float*)d_in[7];
  const float* qw   = (const float*)d_in[8];
  const float* kw   = (const float*)d_in[9];

  char* ws = (char*)d_ws;
  bf16* xb   = (bf16*)(ws);                       //  8 MB
  bf16* Wqb  = (bf16*)(ws + ( 8u << 20));         // 16 MB
  bf16* Wkb  = (bf16*)(ws + (24u << 20));         //  2 MB
  bf16* Wvb  = (bf16*)(ws + (26u << 20));         //  2 MB
  bf16* Wob  = (bf16*)(ws + (28u << 20));         //  8 MB
  bf16* qg   = (bf16*)(ws + (36u << 20));         // 16 MB
  bf16* kpre = (bf16*)(ws + (52u << 20));         //  2 MB
  bf16* vt   = (bf16*)(ws + (54u << 20));         //  2 MB  [channel][s]
  bf16* qrot = (bf16*)(ws + (56u << 20));         //  8 MB  [h][s][d] (pre-scaled)
  bf16* krot = (bf16*)(ws + (64u << 20));         //  2 MB  [g][s][d]
  bf16* ctxg = (bf16*)(ws + (66u << 20));         //  8 MB
  float* out = (float*)d_out;

  cvt_f32_bf16<<<dim3(2048), 256, 0, stream>>>(x,  xb,  S * D);
  cvt_f32_bf16<<<dim3(4096), 256, 0, stream>>>(Wq, Wqb, NQG * D);
  cvt_f32_bf16<<<dim3(512),  256, 0, stream>>>(Wk, Wkb, NKV * D);
  cvt_f32_bf16<<<dim3(512),  256, 0, stream>>>(Wv, Wvb, NKV * D);
  cvt_f32_bf16<<<dim3(2048), 256, 0, stream>>>(Wo, Wob, D * D);

  gemm_qkv<<<dim3(40, 16), 256, 0, stream>>>(xb, Wqb, Wkb, Wvb, qg, kpre, vt);
  rmsrope<<<dim3(20480), 256, 0, stream>>>(qg, kpre, cosb, sinb, qw, kw, qrot, krot);
  attn<<<dim3(512), 256, 0, stream>>>(qrot, krot, vt, qg, ctxg);
  gemm_out<<<dim3(32, 16), 256, 0, stream>>>(ctxg, Wob, out);
}

// Round 8
// 146.086 us; speedup vs baseline: 3.5507x; 1.0841x over previous
//
#include <hip/hip_runtime.h>

typedef __bf16 bf16;
typedef __bf16 bf16x4 __attribute__((ext_vector_type(4)));
typedef __bf16 bf16x8 __attribute__((ext_vector_type(8)));
typedef float f32x4 __attribute__((ext_vector_type(4)));

#define DEV static __device__ __forceinline__

constexpr int S  = 2048;
constexpr int D  = 2048;
constexpr int H  = 32;
constexpr int G  = 8;
constexpr int HD = 64;
constexpr int NQG = 2 * H * HD;  // 4096
constexpr int NKV = G * HD;      // 512
constexpr int LDP = 72;          // padded LDS stride for attn P tile

DEV bf16x8 load8(const bf16* p) { return *reinterpret_cast<const bf16x8*>(p); }

DEV f32x4 mfma16(bf16x8 a, bf16x8 b, f32x4 c) {
  return __builtin_amdgcn_mfma_f32_16x16x32_bf16(a, b, c, 0, 0, 0);
}

DEV void gload_lds16(const bf16* g, bf16* l) {
  __builtin_amdgcn_global_load_lds(
      (const __attribute__((address_space(1))) void*)g,
      (__attribute__((address_space(3))) void*)l, 16, 0, 0);
}

// Stage a [ROWS][64] bf16 tile into LDS with chunk-XOR swizzle (4-wave form).
template <int NISS>  // ROWS = NISS*32 (4 -> 128 rows, 2 -> 64 rows)
DEV void stage_tile(bf16* lds, const bf16* src_row0, size_t ld, int k0, int tid) {
  const int w = tid >> 6, l = tid & 63;
#pragma unroll
  for (int i = 0; i < NISS; ++i) {
    int blk = w * NISS + i;            // 1KB LDS block
    int r = blk * 8 + (l >> 3);
    int c = (l & 7) ^ (r & 7);
    gload_lds16(src_row0 + (size_t)r * ld + k0 + c * 8, lds + blk * 512);
  }
}

// 8-wave form: one issue per wave stages a 64x64 tile (8 x 1KB blocks).
DEV void stage64_8w(bf16* lds, const bf16* src_row0, size_t ld, int k0, int tid) {
  const int w = tid >> 6, l = tid & 63;
  int r = w * 8 + (l >> 3);
  int c = (l & 7) ^ (r & 7);
  gload_lds16(src_row0 + (size_t)r * ld + k0 + c * 8, lds + w * 512);
}

// Read an 8-elem fragment (logical chunk) from a swizzled [*][64] LDS tile.
DEV bf16x8 fragr(const bf16* T, int row, int chunk) {
  return load8(T + row * 64 + (((chunk ^ (row & 7)) << 3)));
}

DEV float fexp2(float x) { return __builtin_amdgcn_exp2f(x); }
DEV float frcp(float x)  { return __builtin_amdgcn_rcpf(x); }

// ---------------------------------------------------------------------------
// All five f32 -> bf16 conversions in ONE launch (segments are block-uniform:
// every segment start is a multiple of 256 chunks).
// ---------------------------------------------------------------------------
__global__ __launch_bounds__(256) void cvt_all(
    const float* __restrict__ x,  const float* __restrict__ wq,
    const float* __restrict__ wk, const float* __restrict__ wv,
    const float* __restrict__ wo,
    bf16* __restrict__ xb,  bf16* __restrict__ wqb, bf16* __restrict__ wkb,
    bf16* __restrict__ wvb, bf16* __restrict__ wob)
{
  long c = (long)blockIdx.x * 256 + threadIdx.x;   // 8-elem chunk id
  const float* src; bf16* dst; long off;
  if      (c <  524288) { src = x;  dst = xb;  off = c; }
  else if (c < 1572864) { src = wq; dst = wqb; off = c -  524288; }
  else if (c < 1703936) { src = wk; dst = wkb; off = c - 1572864; }
  else if (c < 1835008) { src = wv; dst = wvb; off = c - 1703936; }
  else                  { src = wo; dst = wob; off = c - 1835008; }
  long i = off * 8;
  const float4* p = reinterpret_cast<const float4*>(src + i);
  float4 a = p[0], b = p[1];
  bf16x8 o;
  o[0] = (bf16)a.x; o[1] = (bf16)a.y; o[2] = (bf16)a.z; o[3] = (bf16)a.w;
  o[4] = (bf16)b.x; o[5] = (bf16)b.y; o[6] = (bf16)b.z; o[7] = (bf16)b.w;
  *reinterpret_cast<bf16x8*>(dst + i) = o;
}

// ---------------------------------------------------------------------------
// Fused QKV projection, m97 structure: 128x128 tile, BK=64, LDS-staged.
// ---------------------------------------------------------------------------
__global__ __launch_bounds__(256, 3) void gemm_qkv(
    const bf16* __restrict__ X, const bf16* __restrict__ Wq,
    const bf16* __restrict__ Wk, const bf16* __restrict__ Wv,
    bf16* __restrict__ qg, bf16* __restrict__ kpre, bf16* __restrict__ vt)
{
  __shared__ __align__(16) bf16 As[128 * 64];
  __shared__ __align__(16) bf16 Bs[128 * 64];

  const int tid  = threadIdx.x;
  const int wave = tid >> 6;
  const int lane = tid & 63;
  const int ln = lane & 15, hi = lane >> 4;
  const int wm = wave >> 1, wn = wave & 1;
  const int m0 = blockIdx.y * 128;
  const int nt = blockIdx.x;

  const bf16* W; int n0;
  if (nt < 32)      { W = Wq; n0 = nt * 128; }
  else if (nt < 36) { W = Wk; n0 = (nt - 32) * 128; }
  else              { W = Wv; n0 = (nt - 36) * 128; }

  const bf16* arow = X + (size_t)m0 * D;
  const bf16* brow = W + (size_t)n0 * D;

  f32x4 acc[4][4] = {};

  for (int k0 = 0; k0 < D; k0 += 64) {
    __syncthreads();
    stage_tile<4>(As, arow, D, k0, tid);
    stage_tile<4>(Bs, brow, D, k0, tid);
    __syncthreads();
#pragma unroll
    for (int kk = 0; kk < 64; kk += 32) {
      bf16x8 a[4], b[4];
#pragma unroll
      for (int mi = 0; mi < 4; ++mi) a[mi] = fragr(As, wm * 64 + mi * 16 + ln, (kk >> 3) + hi);
#pragma unroll
      for (int ni = 0; ni < 4; ++ni) b[ni] = fragr(Bs, wn * 64 + ni * 16 + ln, (kk >> 3) + hi);
#pragma unroll
      for (int mi = 0; mi < 4; ++mi)
#pragma unroll
        for (int ni = 0; ni < 4; ++ni)
          acc[mi][ni] = mfma16(a[mi], b[ni], acc[mi][ni]);
    }
  }

  if (nt < 36) {
    bf16* C; int ldc;
    if (nt < 32) { C = qg; ldc = NQG; } else { C = kpre; ldc = NKV; }
#pragma unroll
    for (int mi = 0; mi < 4; ++mi)
#pragma unroll
      for (int ni = 0; ni < 4; ++ni)
#pragma unroll
        for (int j = 0; j < 4; ++j) {
          int r = m0 + wm * 64 + mi * 16 + hi * 4 + j;
          int c = n0 + wn * 64 + ni * 16 + ln;
          C[(size_t)r * ldc + c] = (bf16)acc[mi][ni][j];
        }
  } else {
    int nrel = (nt - 36) * 128;
#pragma unroll
    for (int mi = 0; mi < 4; ++mi)
#pragma unroll
      for (int ni = 0; ni < 4; ++ni)
#pragma unroll
        for (int j = 0; j < 4; ++j) {
          int r = m0 + wm * 64 + mi * 16 + hi * 4 + j;          // s
          int c = nrel + wn * 64 + ni * 16 + ln;                // channel
          vt[(size_t)c * S + r] = (bf16)acc[mi][ni][j];
        }
  }
}

// ---------------------------------------------------------------------------
// Output projection, 128x64 tile. f32 output.
// ---------------------------------------------------------------------------
__global__ __launch_bounds__(256, 3) void gemm_out(
    const bf16* __restrict__ A, const bf16* __restrict__ W,
    float* __restrict__ C)
{
  __shared__ __align__(16) bf16 As[128 * 64];
  __shared__ __align__(16) bf16 Bs[64 * 64];

  const int tid  = threadIdx.x;
  const int wave = tid >> 6;
  const int lane = tid & 63;
  const int ln = lane & 15, hi = lane >> 4;
  const int m0 = blockIdx.y * 128;
  const int n0 = blockIdx.x * 64;

  const bf16* arow = A + (size_t)m0 * D;
  const bf16* brow = W + (size_t)n0 * D;

  f32x4 acc[2][4] = {};

  for (int k0 = 0; k0 < D; k0 += 64) {
    __syncthreads();
    stage_tile<4>(As, arow, D, k0, tid);
    stage_tile<2>(Bs, brow, D, k0, tid);
    __syncthreads();
#pragma unroll
    for (int kk = 0; kk < 64; kk += 32) {
      bf16x8 a[2], b[4];
#pragma unroll
      for (int mi = 0; mi < 2; ++mi) a[mi] = fragr(As, wave * 32 + mi * 16 + ln, (kk >> 3) + hi);
#pragma unroll
      for (int ni = 0; ni < 4; ++ni) b[ni] = fragr(Bs, ni * 16 + ln, (kk >> 3) + hi);
#pragma unroll
      for (int mi = 0; mi < 2; ++mi)
#pragma unroll
        for (int ni = 0; ni < 4; ++ni)
          acc[mi][ni] = mfma16(a[mi], b[ni], acc[mi][ni]);
    }
  }

#pragma unroll
  for (int mi = 0; mi < 2; ++mi)
#pragma unroll
    for (int ni = 0; ni < 4; ++ni)
#pragma unroll
      for (int j = 0; j < 4; ++j) {
        int r = m0 + wave * 32 + mi * 16 + hi * 4 + j;
        int c = n0 + ni * 16 + ln;
        C[(size_t)r * D + c] = acc[mi][ni][j];
      }
}

// ---------------------------------------------------------------------------
// RMSNorm + RoPE. Q output PRE-SCALED by 0.125*log2(e); K unscaled.
// ---------------------------------------------------------------------------
__global__ __launch_bounds__(256) void rmsrope(
    const bf16* __restrict__ qg, const bf16* __restrict__ kpre,
    const float* __restrict__ cosb, const float* __restrict__ sinb,
    const float* __restrict__ qw, const float* __restrict__ kw,
    bf16* __restrict__ qrot, bf16* __restrict__ krot)
{
  int wid  = (int)((blockIdx.x * (unsigned)blockDim.x + threadIdx.x) >> 6);
  int lane = threadIdx.x & 63;
  int s  = wid & (S - 1);
  int hh = wid >> 11;  // 0..39

  float v, wgt;
  if (hh < H) { v = (float)qg[(size_t)s * NQG + hh * 128 + lane];        wgt = qw[lane]; }
  else        { v = (float)kpre[(size_t)s * NKV + (hh - H) * 64 + lane]; wgt = kw[lane]; }

  float ss = v * v;
#pragma unroll
  for (int m = 1; m < 64; m <<= 1) ss += __shfl_xor(ss, m);
  float xf = v * (1.0f / sqrtf(ss * (1.0f / 64.0f) + 1e-6f)) * (1.0f + wgt);

  float part = __shfl_xor(xf, 32);
  float rot  = (lane < 32) ? -part : part;
  float c  = cosb[(size_t)s * HD + lane];
  float sn = sinb[(size_t)s * HD + lane];
  float r  = xf * c + rot * sn;

  if (hh < H) {
    qrot[((size_t)hh * S + s) * HD + lane] = (bf16)(r * 0.18033688011111204f);
  } else {
    krot[((size_t)(hh - H) * S + s) * HD + lane] = (bf16)r;
  }
}

// ---------------------------------------------------------------------------
// Flash attention: swapped QK^T, 8 waves / 512 threads per block.
// TWO heads of the same GQA group share one block, so the double-buffered
// K/V LDS staging is amortized 2x (waves 0-3 -> head h0, 4-7 -> h1).
// Raw s_barrier + manual vmcnt keeps prefetch loads in flight across the
// barrier (T3 minimal 2-phase schedule).
// ---------------------------------------------------------------------------
#define BARRIER() asm volatile("s_barrier" ::: "memory")
#define VMDRAIN() asm volatile("s_waitcnt vmcnt(0)" ::: "memory")

DEV void attn_phase(const bf16* __restrict__ qrot, const bf16* __restrict__ krow,
                    const bf16* __restrict__ vrow, const bf16* __restrict__ qg,
                    bf16* __restrict__ ctxg,
                    bf16* Kb0, bf16* Kb1, bf16* Vb0, bf16* Vb1, bf16* pw,
                    int h, int qchunk, int nt, int ln, int hi, int tid)
{
  const int qb = qchunk * 64 + ((tid >> 6) & 3) * 16;
  const int q  = qb + ln;

  const bf16* qbase = qrot + ((size_t)h * S + qb + ln) * HD + hi * 8;
  bf16x8 q0 = load8(qbase);
  bf16x8 q1 = load8(qbase + 32);

  f32x4 po[4] = {};
  float m = -INFINITY, l = 0.f;

  // prologue: stage tile 0, drain once, sync
  stage64_8w(Kb0, krow, 64, 0, tid);
  stage64_8w(Vb0, vrow, S, 0, tid);
  VMDRAIN();
  BARRIER();

  int cur = 0;
  for (int t = 0; t < nt; ++t) {
    const bf16* Kb = cur ? Kb1 : Kb0;
    const bf16* Vb = cur ? Vb1 : Vb0;

    // issue next tile's loads; they complete during this tile's compute
    if (t + 1 < nt) {
      bf16* Kn = cur ? Kb0 : Kb1;
      bf16* Vn = cur ? Vb0 : Vb1;
      stage64_8w(Kn, krow + (size_t)(t + 1) * 64 * 64, 64, 0, tid);
      stage64_8w(Vn, vrow, S, (t + 1) * 64, tid);
    }

    bf16x8 kf0[4], kf1[4];
#pragma unroll
    for (int kr = 0; kr < 4; ++kr) {
      kf0[kr] = fragr(Kb, kr * 16 + ln, hi);
      kf1[kr] = fragr(Kb, kr * 16 + ln, hi + 4);
    }
    bf16x8 bv0[4], bv1[4];
#pragma unroll
    for (int dt = 0; dt < 4; ++dt) {
      bv0[dt] = fragr(Vb, dt * 16 + ln, hi);
      bv1[dt] = fragr(Vb, dt * 16 + ln, hi + 4);
    }

    f32x4 sc[4] = {};
    __builtin_amdgcn_s_setprio(1);
#pragma unroll
    for (int kr = 0; kr < 4; ++kr) {
      sc[kr] = mfma16(kf0[kr], q0, sc[kr]);
      sc[kr] = mfma16(kf1[kr], q1, sc[kr]);
    }
    __builtin_amdgcn_s_setprio(0);

    float pmax = -INFINITY;
    if (t == nt - 1) {
      const int key0 = t << 6;
#pragma unroll
      for (int kr = 0; kr < 4; ++kr)
#pragma unroll
        for (int j = 0; j < 4; ++j) {
          int key = key0 + kr * 16 + hi * 4 + j;
          float v = (key <= q) ? sc[kr][j] : -INFINITY;
          sc[kr][j] = v;
          pmax = fmaxf(pmax, v);
        }
    } else {
#pragma unroll
      for (int kr = 0; kr < 4; ++kr)
#pragma unroll
        for (int j = 0; j < 4; ++j) pmax = fmaxf(pmax, sc[kr][j]);
    }
    pmax = fmaxf(pmax, __shfl_xor(pmax, 16));
    pmax = fmaxf(pmax, __shfl_xor(pmax, 32));

    // defer-max: rescale only when the running max grows by > 8 (log2 dom.)
    if (__any(pmax > m + 8.0f)) {
      float mn = fmaxf(m, pmax);
      float c  = fexp2(m - mn);
      l *= c;
      float cc[4];
#pragma unroll
      for (int j = 0; j < 4; ++j) cc[j] = __shfl(c, hi * 4 + j);
#pragma unroll
      for (int dt = 0; dt < 4; ++dt)
#pragma unroll
        for (int j = 0; j < 4; ++j) po[dt][j] *= cc[j];
      m = mn;
    }

    float ps = 0.f;
#pragma unroll
    for (int kr = 0; kr < 4; ++kr)
#pragma unroll
      for (int j = 0; j < 4; ++j) {
        float e = fexp2(sc[kr][j] - m);
        sc[kr][j] = e;
        ps += e;
      }
    ps += __shfl_xor(ps, 16);
    ps += __shfl_xor(ps, 32);
    l += ps;

    // P^T -> P through wave-private LDS (cvt_pk packs 2 f32 -> 2 bf16)
#pragma unroll
    for (int kr = 0; kr < 4; ++kr) {
      unsigned w0, w1;
      asm("v_cvt_pk_bf16_f32 %0, %1, %2" : "=v"(w0) : "v"(sc[kr][0]), "v"(sc[kr][1]));
      asm("v_cvt_pk_bf16_f32 %0, %1, %2" : "=v"(w1) : "v"(sc[kr][2]), "v"(sc[kr][3]));
      uint2 w = {w0, w1};
      *reinterpret_cast<uint2*>(pw + ln * LDP + kr * 16 + hi * 4) = w;
    }
    bf16x8 pa0 = load8(pw + ln * LDP + hi * 8);
    bf16x8 pa1 = load8(pw + ln * LDP + 32 + hi * 8);

    __builtin_amdgcn_s_setprio(1);
#pragma unroll
    for (int dt = 0; dt < 4; ++dt) {
      po[dt] = mfma16(pa0, bv0[dt], po[dt]);
      po[dt] = mfma16(pa1, bv1[dt], po[dt]);
    }
    __builtin_amdgcn_s_setprio(0);

    VMDRAIN();   // next tile's loads had the whole compute to land
    BARRIER();   // all waves: buf[cur^1] ready, buf[cur] free to overwrite
    cur ^= 1;
  }

  // epilogue: normalize, gate, store
  float lf[4];
#pragma unroll
  for (int j = 0; j < 4; ++j) lf[j] = __shfl(l, hi * 4 + j);
#pragma unroll
  for (int dt = 0; dt < 4; ++dt)
#pragma unroll
    for (int j = 0; j < 4; ++j) {
      int qq = qb + hi * 4 + j;
      int d  = dt * 16 + ln;
      float o  = po[dt][j] * frcp(lf[j]);
      float gv = (float)qg[(size_t)qq * NQG + h * 128 + 64 + d];
      float sg = frcp(1.0f + fexp2(gv * -1.442695040888963f));
      ctxg[(size_t)qq * D + h * 64 + d] = (bf16)(o * sg);
    }
}

__global__ __launch_bounds__(512) void attn(
    const bf16* __restrict__ qrot, const bf16* __restrict__ krot,
    const bf16* __restrict__ vt, const bf16* __restrict__ qg,
    bf16* __restrict__ ctxg)
{
  __shared__ __align__(16) bf16 Kbuf[2][64 * 64];
  __shared__ __align__(16) bf16 Vbuf[2][64 * 64];
  __shared__ __align__(16) bf16 Pl[8][16 * LDP];

  const int tid  = threadIdx.x;
  const int lane = tid & 63;
  const int ln = lane & 15, hi = lane >> 4;

  // XCD-aware decode: blocks with bid%8 == x share KV group g = x.
  // i = bid>>3: hp = i&1 selects the head-pair, pr = i>>1 the q-chunk pair.
  const int bid = blockIdx.x;
  const int g   = bid & 7;
  const int i   = bid >> 3;            // 0..31
  const int hp  = i & 1;
  const int pr  = i >> 1;              // 0..15
  const int h   = g * 4 + hp * 2 + ((tid >> 6) >> 2);  // per-wave head
  bf16* pw = &Pl[tid >> 6][0];

  const bf16* krow = krot + (size_t)g * S * HD;   // [key][d], ld=64
  const bf16* vrow = vt + (size_t)g * 64 * S;     // [channel][s], ld=S

  attn_phase(qrot, krow, vrow, qg, ctxg,
             &Kbuf[0][0], &Kbuf[1][0], &Vbuf[0][0], &Vbuf[1][0], pw,
             h, pr, pr + 1, ln, hi, tid);
  attn_phase(qrot, krow, vrow, qg, ctxg,
             &Kbuf[0][0], &Kbuf[1][0], &Vbuf[0][0], &Vbuf[1][0], pw,
             h, 31 - pr, 32 - pr, ln, hi, tid);
}

// ---------------------------------------------------------------------------
extern "C" void kernel_launch(void* const* d_in, const int* in_sizes, int n_in,
                              void* d_out, int out_size, void* d_ws, size_t ws_size,
                              hipStream_t stream) {
  const float* x    = (const float*)d_in[0];
  const float* cosb = (const float*)d_in[2];
  const float* sinb = (const float*)d_in[3];
  const float* Wq   = (const float*)d_in[4];
  const float* Wk   = (const float*)d_in[5];
  const float* Wv   = (const float*)d_in[6];
  const float* Wo   = (const float*)d_in[7];
  const float* qw   = (const float*)d_in[8];
  const float* kw   = (const float*)d_in[9];

  char* ws = (char*)d_ws;
  bf16* xb   = (bf16*)(ws);                       //  8 MB
  bf16* Wqb  = (bf16*)(ws + ( 8u << 20));         // 16 MB
  bf16* Wkb  = (bf16*)(ws + (24u << 20));         //  2 MB
  bf16* Wvb  = (bf16*)(ws + (26u << 20));         //  2 MB
  bf16* Wob  = (bf16*)(ws + (28u << 20));         //  8 MB
  bf16* qg   = (bf16*)(ws + (36u << 20));         // 16 MB
  bf16* kpre = (bf16*)(ws + (52u << 20));         //  2 MB
  bf16* vt   = (bf16*)(ws + (54u << 20));         //  2 MB  [channel][s]
  bf16* qrot = (bf16*)(ws + (56u << 20));         //  8 MB  [h][s][d] (pre-scaled)
  bf16* krot = (bf16*)(ws + (64u << 20));         //  2 MB  [g][s][d]
  bf16* ctxg = (bf16*)(ws + (66u << 20));         //  8 MB
  float* out = (float*)d_out;

  cvt_all<<<dim3(9216), 256, 0, stream>>>(x, Wq, Wk, Wv, Wo,
                                          xb, Wqb, Wkb, Wvb, Wob);

  gemm_qkv<<<dim3(40, 16), 256, 0, stream>>>(xb, Wqb, Wkb, Wvb, qg, kpre, vt);
  rmsrope<<<dim3(20480), 256, 0, stream>>>(qg, kpre, cosb, sinb, qw, kw, qrot, krot);
  attn<<<dim3(256), 512, 0, stream>>>(qrot, krot, vt, qg, ctxg);
  gemm_out<<<dim3(32, 16), 256, 0, stream>>>(ctxg, Wob, out);
}

// Round 9
// 145.301 us; speedup vs baseline: 3.5699x; 1.0054x over previous
//
#include <hip/hip_runtime.h>

typedef __bf16 bf16;
typedef __bf16 bf16x4 __attribute__((ext_vector_type(4)));
typedef __bf16 bf16x8 __attribute__((ext_vector_type(8)));
typedef float f32x4 __attribute__((ext_vector_type(4)));

#define DEV static __device__ __forceinline__

constexpr int S  = 2048;
constexpr int D  = 2048;
constexpr int H  = 32;
constexpr int G  = 8;
constexpr int HD = 64;
constexpr int NQG = 2 * H * HD;  // 4096
constexpr int LDP = 72;          // padded LDS stride for attn P tile

DEV bf16x8 load8(const bf16* p) { return *reinterpret_cast<const bf16x8*>(p); }

DEV f32x4 mfma16(bf16x8 a, bf16x8 b, f32x4 c) {
  return __builtin_amdgcn_mfma_f32_16x16x32_bf16(a, b, c, 0, 0, 0);
}

DEV void gload_lds16(const bf16* g, bf16* l) {
  __builtin_amdgcn_global_load_lds(
      (const __attribute__((address_space(1))) void*)g,
      (__attribute__((address_space(3))) void*)l, 16, 0, 0);
}

// Stage a [ROWS][64] bf16 tile into LDS with chunk-XOR swizzle (4-wave form).
template <int NISS>  // ROWS = NISS*32 (4 -> 128 rows, 2 -> 64 rows)
DEV void stage_tile(bf16* lds, const bf16* src_row0, size_t ld, int k0, int tid) {
  const int w = tid >> 6, l = tid & 63;
#pragma unroll
  for (int i = 0; i < NISS; ++i) {
    int blk = w * NISS + i;            // 1KB LDS block
    int r = blk * 8 + (l >> 3);
    int c = (l & 7) ^ (r & 7);
    gload_lds16(src_row0 + (size_t)r * ld + k0 + c * 8, lds + blk * 512);
  }
}

// 8-wave form: one issue per wave stages a 64x64 tile (8 x 1KB blocks).
DEV void stage64_8w(bf16* lds, const bf16* src_row0, size_t ld, int k0, int tid) {
  const int w = tid >> 6, l = tid & 63;
  int r = w * 8 + (l >> 3);
  int c = (l & 7) ^ (r & 7);
  gload_lds16(src_row0 + (size_t)r * ld + k0 + c * 8, lds + w * 512);
}

// Read an 8-elem fragment (logical chunk) from a swizzled [*][64] LDS tile.
DEV bf16x8 fragr(const bf16* T, int row, int chunk) {
  return load8(T + row * 64 + (((chunk ^ (row & 7)) << 3)));
}

DEV float fexp2(float x) { return __builtin_amdgcn_exp2f(x); }
DEV float frcp(float x)  { return __builtin_amdgcn_rcpf(x); }

// ---------------------------------------------------------------------------
// All five f32 -> bf16 conversions in ONE launch.
// ---------------------------------------------------------------------------
__global__ __launch_bounds__(256) void cvt_all(
    const float* __restrict__ x,  const float* __restrict__ wq,
    const float* __restrict__ wk, const float* __restrict__ wv,
    const float* __restrict__ wo,
    bf16* __restrict__ xb,  bf16* __restrict__ wqb, bf16* __restrict__ wkb,
    bf16* __restrict__ wvb, bf16* __restrict__ wob)
{
  long c = (long)blockIdx.x * 256 + threadIdx.x;   // 8-elem chunk id
  const float* src; bf16* dst; long off;
  if      (c <  524288) { src = x;  dst = xb;  off = c; }
  else if (c < 1572864) { src = wq; dst = wqb; off = c -  524288; }
  else if (c < 1703936) { src = wk; dst = wkb; off = c - 1572864; }
  else if (c < 1835008) { src = wv; dst = wvb; off = c - 1703936; }
  else                  { src = wo; dst = wob; off = c - 1835008; }
  long i = off * 8;
  const float4* p = reinterpret_cast<const float4*>(src + i);
  float4 a = p[0], b = p[1];
  bf16x8 o;
  o[0] = (bf16)a.x; o[1] = (bf16)a.y; o[2] = (bf16)a.z; o[3] = (bf16)a.w;
  o[4] = (bf16)b.x; o[5] = (bf16)b.y; o[6] = (bf16)b.z; o[7] = (bf16)b.w;
  *reinterpret_cast<bf16x8*>(dst + i) = o;
}

// ---------------------------------------------------------------------------
// Fused RMSNorm + RoPE epilogue helper. Wave holds a 64x64 output block
// covering EXACTLY one head's 64 channels: channel d = ni*16 + ln (reg ni,
// lane ln), row s = s0 + mi*16 + hi*4 + j. Mean-square = 4 in-lane squares +
// 4 shfl_xor (ln-group); RoPE partner d+-32 is reg ni+-2, same lane.
// ---------------------------------------------------------------------------
DEV void rms_rope_store(f32x4 acc[4][4], bf16* __restrict__ dst,
                        const float* __restrict__ w,
                        const float* __restrict__ cosb,
                        const float* __restrict__ sinb,
                        int s0, int ln, int hi, float outscale)
{
  float wgt[4];
#pragma unroll
  for (int ni = 0; ni < 4; ++ni) wgt[ni] = 1.0f + w[ni * 16 + ln];
#pragma unroll
  for (int mi = 0; mi < 4; ++mi)
#pragma unroll
    for (int j = 0; j < 4; ++j) {
      int s = s0 + mi * 16 + hi * 4 + j;
      float v0 = acc[mi][0][j], v1 = acc[mi][1][j];
      float v2 = acc[mi][2][j], v3 = acc[mi][3][j];
      float ss = v0 * v0 + v1 * v1 + v2 * v2 + v3 * v3;
      ss += __shfl_xor(ss, 1);
      ss += __shfl_xor(ss, 2);
      ss += __shfl_xor(ss, 4);
      ss += __shfl_xor(ss, 8);
      float inv = __builtin_amdgcn_rsqf(ss * (1.0f / 64.0f) + 1e-6f);
      float xf[4] = {v0 * inv * wgt[0], v1 * inv * wgt[1],
                     v2 * inv * wgt[2], v3 * inv * wgt[3]};
#pragma unroll
      for (int ni = 0; ni < 4; ++ni) {
        int d = ni * 16 + ln;
        float c  = cosb[s * HD + d];
        float sn = sinb[s * HD + d];
        float rot = (ni < 2) ? -xf[ni + 2] : xf[ni - 2];
        dst[(size_t)s * HD + d] = (bf16)((xf[ni] * c + rot * sn) * outscale);
      }
    }
}

// ---------------------------------------------------------------------------
// Fused QKV projection + RMSNorm + RoPE epilogue.
// grid = (40, 16). nt<32: head nt -> wn=0 wave = q half (norm+rope -> qrot,
// pre-scaled by 0.125*log2e), wn=1 wave = gate half (-> qg cols 64..128).
// nt 32..35: KV head g8=(nt-32)*2+wn (norm+rope -> krot). nt>=36: vt^T.
// ---------------------------------------------------------------------------
__global__ __launch_bounds__(256, 3) void gemm_qkv(
    const bf16* __restrict__ X, const bf16* __restrict__ Wq,
    const bf16* __restrict__ Wk, const bf16* __restrict__ Wv,
    const float* __restrict__ cosb, const float* __restrict__ sinb,
    const float* __restrict__ qw, const float* __restrict__ kw,
    bf16* __restrict__ qg, bf16* __restrict__ qrot,
    bf16* __restrict__ krot, bf16* __restrict__ vt)
{
  __shared__ __align__(16) bf16 As[128 * 64];
  __shared__ __align__(16) bf16 Bs[128 * 64];

  const int tid  = threadIdx.x;
  const int wave = tid >> 6;
  const int lane = tid & 63;
  const int ln = lane & 15, hi = lane >> 4;
  const int wm = wave >> 1, wn = wave & 1;
  const int m0 = blockIdx.y * 128;
  const int nt = blockIdx.x;

  const bf16* W; int n0;
  if (nt < 32)      { W = Wq; n0 = nt * 128; }
  else if (nt < 36) { W = Wk; n0 = (nt - 32) * 128; }
  else              { W = Wv; n0 = (nt - 36) * 128; }

  const bf16* arow = X + (size_t)m0 * D;
  const bf16* brow = W + (size_t)n0 * D;

  f32x4 acc[4][4] = {};

  for (int k0 = 0; k0 < D; k0 += 64) {
    __syncthreads();
    stage_tile<4>(As, arow, D, k0, tid);
    stage_tile<4>(Bs, brow, D, k0, tid);
    __syncthreads();
#pragma unroll
    for (int kk = 0; kk < 64; kk += 32) {
      bf16x8 a[4], b[4];
#pragma unroll
      for (int mi = 0; mi < 4; ++mi) a[mi] = fragr(As, wm * 64 + mi * 16 + ln, (kk >> 3) + hi);
#pragma unroll
      for (int ni = 0; ni < 4; ++ni) b[ni] = fragr(Bs, wn * 64 + ni * 16 + ln, (kk >> 3) + hi);
#pragma unroll
      for (int mi = 0; mi < 4; ++mi)
#pragma unroll
        for (int ni = 0; ni < 4; ++ni)
          acc[mi][ni] = mfma16(a[mi], b[ni], acc[mi][ni]);
    }
  }

  const int s0 = m0 + wm * 64;
  if (nt < 32) {
    if (wn == 0) {
      // q half: RMSNorm + RoPE, pre-scaled for log2-domain softmax
      rms_rope_store(acc, qrot + (size_t)nt * S * HD, qw, cosb, sinb,
                     s0, ln, hi, 0.18033688011111204f);
    } else {
      // gate half -> qg[:, nt*128+64 .. +128]
#pragma unroll
      for (int mi = 0; mi < 4; ++mi)
#pragma unroll
        for (int ni = 0; ni < 4; ++ni)
#pragma unroll
          for (int j = 0; j < 4; ++j) {
            int r = s0 + mi * 16 + hi * 4 + j;
            int c = nt * 128 + 64 + ni * 16 + ln;
            qg[(size_t)r * NQG + c] = (bf16)acc[mi][ni][j];
          }
    }
  } else if (nt < 36) {
    int g8 = (nt - 32) * 2 + wn;
    rms_rope_store(acc, krot + (size_t)g8 * S * HD, kw, cosb, sinb,
                   s0, ln, hi, 1.0f);
  } else {
    int nrel = (nt - 36) * 128;
#pragma unroll
    for (int mi = 0; mi < 4; ++mi)
#pragma unroll
      for (int ni = 0; ni < 4; ++ni)
#pragma unroll
        for (int j = 0; j < 4; ++j) {
          int r = s0 + mi * 16 + hi * 4 + j;                    // s
          int c = nrel + wn * 64 + ni * 16 + ln;                // channel
          vt[(size_t)c * S + r] = (bf16)acc[mi][ni][j];
        }
  }
}

// ---------------------------------------------------------------------------
// Output projection, 128x128 tile (same structure as gemm_qkv). f32 output.
// ---------------------------------------------------------------------------
__global__ __launch_bounds__(256, 3) void gemm_out(
    const bf16* __restrict__ A, const bf16* __restrict__ W,
    float* __restrict__ C)
{
  __shared__ __align__(16) bf16 As[128 * 64];
  __shared__ __align__(16) bf16 Bs[128 * 64];

  const int tid  = threadIdx.x;
  const int wave = tid >> 6;
  const int lane = tid & 63;
  const int ln = lane & 15, hi = lane >> 4;
  const int wm = wave >> 1, wn = wave & 1;
  const int m0 = blockIdx.y * 128;
  const int n0 = blockIdx.x * 128;

  const bf16* arow = A + (size_t)m0 * D;
  const bf16* brow = W + (size_t)n0 * D;

  f32x4 acc[4][4] = {};

  for (int k0 = 0; k0 < D; k0 += 64) {
    __syncthreads();
    stage_tile<4>(As, arow, D, k0, tid);
    stage_tile<4>(Bs, brow, D, k0, tid);
    __syncthreads();
#pragma unroll
    for (int kk = 0; kk < 64; kk += 32) {
      bf16x8 a[4], b[4];
#pragma unroll
      for (int mi = 0; mi < 4; ++mi) a[mi] = fragr(As, wm * 64 + mi * 16 + ln, (kk >> 3) + hi);
#pragma unroll
      for (int ni = 0; ni < 4; ++ni) b[ni] = fragr(Bs, wn * 64 + ni * 16 + ln, (kk >> 3) + hi);
#pragma unroll
      for (int mi = 0; mi < 4; ++mi)
#pragma unroll
        for (int ni = 0; ni < 4; ++ni)
          acc[mi][ni] = mfma16(a[mi], b[ni], acc[mi][ni]);
    }
  }

#pragma unroll
  for (int mi = 0; mi < 4; ++mi)
#pragma unroll
    for (int ni = 0; ni < 4; ++ni)
#pragma unroll
      for (int j = 0; j < 4; ++j) {
        int r = m0 + wm * 64 + mi * 16 + hi * 4 + j;
        int c = n0 + wn * 64 + ni * 16 + ln;
        C[(size_t)r * D + c] = acc[mi][ni][j];
      }
}

// ---------------------------------------------------------------------------
// Flash attention (unchanged from round 8): swapped QK^T, 8 waves/block,
// two heads share K/V staging, raw-barrier double-buffered prefetch.
// ---------------------------------------------------------------------------
#define BARRIER() asm volatile("s_barrier" ::: "memory")
#define VMDRAIN() asm volatile("s_waitcnt vmcnt(0)" ::: "memory")

DEV void attn_phase(const bf16* __restrict__ qrot, const bf16* __restrict__ krow,
                    const bf16* __restrict__ vrow, const bf16* __restrict__ qg,
                    bf16* __restrict__ ctxg,
                    bf16* Kb0, bf16* Kb1, bf16* Vb0, bf16* Vb1, bf16* pw,
                    int h, int qchunk, int nt, int ln, int hi, int tid)
{
  const int qb = qchunk * 64 + ((tid >> 6) & 3) * 16;
  const int q  = qb + ln;

  const bf16* qbase = qrot + ((size_t)h * S + qb + ln) * HD + hi * 8;
  bf16x8 q0 = load8(qbase);
  bf16x8 q1 = load8(qbase + 32);

  f32x4 po[4] = {};
  float m = -INFINITY, l = 0.f;

  stage64_8w(Kb0, krow, 64, 0, tid);
  stage64_8w(Vb0, vrow, S, 0, tid);
  VMDRAIN();
  BARRIER();

  int cur = 0;
  for (int t = 0; t < nt; ++t) {
    const bf16* Kb = cur ? Kb1 : Kb0;
    const bf16* Vb = cur ? Vb1 : Vb0;

    if (t + 1 < nt) {
      bf16* Kn = cur ? Kb0 : Kb1;
      bf16* Vn = cur ? Vb0 : Vb1;
      stage64_8w(Kn, krow + (size_t)(t + 1) * 64 * 64, 64, 0, tid);
      stage64_8w(Vn, vrow, S, (t + 1) * 64, tid);
    }

    bf16x8 kf0[4], kf1[4];
#pragma unroll
    for (int kr = 0; kr < 4; ++kr) {
      kf0[kr] = fragr(Kb, kr * 16 + ln, hi);
      kf1[kr] = fragr(Kb, kr * 16 + ln, hi + 4);
    }
    bf16x8 bv0[4], bv1[4];
#pragma unroll
    for (int dt = 0; dt < 4; ++dt) {
      bv0[dt] = fragr(Vb, dt * 16 + ln, hi);
      bv1[dt] = fragr(Vb, dt * 16 + ln, hi + 4);
    }

    f32x4 sc[4] = {};
    __builtin_amdgcn_s_setprio(1);
#pragma unroll
    for (int kr = 0; kr < 4; ++kr) {
      sc[kr] = mfma16(kf0[kr], q0, sc[kr]);
      sc[kr] = mfma16(kf1[kr], q1, sc[kr]);
    }
    __builtin_amdgcn_s_setprio(0);

    float pmax = -INFINITY;
    if (t == nt - 1) {
      const int key0 = t << 6;
#pragma unroll
      for (int kr = 0; kr < 4; ++kr)
#pragma unroll
        for (int j = 0; j < 4; ++j) {
          int key = key0 + kr * 16 + hi * 4 + j;
          float v = (key <= q) ? sc[kr][j] : -INFINITY;
          sc[kr][j] = v;
          pmax = fmaxf(pmax, v);
        }
    } else {
#pragma unroll
      for (int kr = 0; kr < 4; ++kr)
#pragma unroll
        for (int j = 0; j < 4; ++j) pmax = fmaxf(pmax, sc[kr][j]);
    }
    pmax = fmaxf(pmax, __shfl_xor(pmax, 16));
    pmax = fmaxf(pmax, __shfl_xor(pmax, 32));

    if (__any(pmax > m + 8.0f)) {
      float mn = fmaxf(m, pmax);
      float c  = fexp2(m - mn);
      l *= c;
      float cc[4];
#pragma unroll
      for (int j = 0; j < 4; ++j) cc[j] = __shfl(c, hi * 4 + j);
#pragma unroll
      for (int dt = 0; dt < 4; ++dt)
#pragma unroll
        for (int j = 0; j < 4; ++j) po[dt][j] *= cc[j];
      m = mn;
    }

    float ps = 0.f;
#pragma unroll
    for (int kr = 0; kr < 4; ++kr)
#pragma unroll
      for (int j = 0; j < 4; ++j) {
        float e = fexp2(sc[kr][j] - m);
        sc[kr][j] = e;
        ps += e;
      }
    ps += __shfl_xor(ps, 16);
    ps += __shfl_xor(ps, 32);
    l += ps;

#pragma unroll
    for (int kr = 0; kr < 4; ++kr) {
      unsigned w0, w1;
      asm("v_cvt_pk_bf16_f32 %0, %1, %2" : "=v"(w0) : "v"(sc[kr][0]), "v"(sc[kr][1]));
      asm("v_cvt_pk_bf16_f32 %0, %1, %2" : "=v"(w1) : "v"(sc[kr][2]), "v"(sc[kr][3]));
      uint2 w = {w0, w1};
      *reinterpret_cast<uint2*>(pw + ln * LDP + kr * 16 + hi * 4) = w;
    }
    bf16x8 pa0 = load8(pw + ln * LDP + hi * 8);
    bf16x8 pa1 = load8(pw + ln * LDP + 32 + hi * 8);

    __builtin_amdgcn_s_setprio(1);
#pragma unroll
    for (int dt = 0; dt < 4; ++dt) {
      po[dt] = mfma16(pa0, bv0[dt], po[dt]);
      po[dt] = mfma16(pa1, bv1[dt], po[dt]);
    }
    __builtin_amdgcn_s_setprio(0);

    VMDRAIN();
    BARRIER();
    cur ^= 1;
  }

  float lf[4];
#pragma unroll
  for (int j = 0; j < 4; ++j) lf[j] = __shfl(l, hi * 4 + j);
#pragma unroll
  for (int dt = 0; dt < 4; ++dt)
#pragma unroll
    for (int j = 0; j < 4; ++j) {
      int qq = qb + hi * 4 + j;
      int d  = dt * 16 + ln;
      float o  = po[dt][j] * frcp(lf[j]);
      float gv = (float)qg[(size_t)qq * NQG + h * 128 + 64 + d];
      float sg = frcp(1.0f + fexp2(gv * -1.442695040888963f));
      ctxg[(size_t)qq * D + h * 64 + d] = (bf16)(o * sg);
    }
}

__global__ __launch_bounds__(512) void attn(
    const bf16* __restrict__ qrot, const bf16* __restrict__ krot,
    const bf16* __restrict__ vt, const bf16* __restrict__ qg,
    bf16* __restrict__ ctxg)
{
  __shared__ __align__(16) bf16 Kbuf[2][64 * 64];
  __shared__ __align__(16) bf16 Vbuf[2][64 * 64];
  __shared__ __align__(16) bf16 Pl[8][16 * LDP];

  const int tid  = threadIdx.x;
  const int lane = tid & 63;
  const int ln = lane & 15, hi = lane >> 4;

  const int bid = blockIdx.x;
  const int g   = bid & 7;
  const int i   = bid >> 3;            // 0..31
  const int hp  = i & 1;
  const int pr  = i >> 1;              // 0..15
  const int h   = g * 4 + hp * 2 + ((tid >> 6) >> 2);  // per-wave head
  bf16* pw = &Pl[tid >> 6][0];

  const bf16* krow = krot + (size_t)g * S * HD;   // [key][d], ld=64
  const bf16* vrow = vt + (size_t)g * 64 * S;     // [channel][s], ld=S

  attn_phase(qrot, krow, vrow, qg, ctxg,
             &Kbuf[0][0], &Kbuf[1][0], &Vbuf[0][0], &Vbuf[1][0], pw,
             h, pr, pr + 1, ln, hi, tid);
  attn_phase(qrot, krow, vrow, qg, ctxg,
             &Kbuf[0][0], &Kbuf[1][0], &Vbuf[0][0], &Vbuf[1][0], pw,
             h, 31 - pr, 32 - pr, ln, hi, tid);
}

// ---------------------------------------------------------------------------
extern "C" void kernel_launch(void* const* d_in, const int* in_sizes, int n_in,
                              void* d_out, int out_size, void* d_ws, size_t ws_size,
                              hipStream_t stream) {
  const float* x    = (const float*)d_in[0];
  const float* cosb = (const float*)d_in[2];
  const float* sinb = (const float*)d_in[3];
  const float* Wq   = (const float*)d_in[4];
  const float* Wk   = (const float*)d_in[5];
  const float* Wv   = (const float*)d_in[6];
  const float* Wo   = (const float*)d_in[7];
  const float* qw   = (const float*)d_in[8];
  const float* kw   = (const float*)d_in[9];

  char* ws = (char*)d_ws;
  bf16* xb   = (bf16*)(ws);                       //  8 MB
  bf16* Wqb  = (bf16*)(ws + ( 8u << 20));         // 16 MB
  bf16* Wkb  = (bf16*)(ws + (24u << 20));         //  2 MB
  bf16* Wvb  = (bf16*)(ws + (26u << 20));         //  2 MB
  bf16* Wob  = (bf16*)(ws + (28u << 20));         //  8 MB
  bf16* qg   = (bf16*)(ws + (36u << 20));         // 16 MB (gate halves only)
  bf16* vt   = (bf16*)(ws + (54u << 20));         //  2 MB  [channel][s]
  bf16* qrot = (bf16*)(ws + (56u << 20));         //  8 MB  [h][s][d] (pre-scaled)
  bf16* krot = (bf16*)(ws + (64u << 20));         //  2 MB  [g][s][d]
  bf16* ctxg = (bf16*)(ws + (66u << 20));         //  8 MB
  float* out = (float*)d_out;

  cvt_all<<<dim3(9216), 256, 0, stream>>>(x, Wq, Wk, Wv, Wo,
                                          xb, Wqb, Wkb, Wvb, Wob);

  gemm_qkv<<<dim3(40, 16), 256, 0, stream>>>(xb, Wqb, Wkb, Wvb,
                                             cosb, sinb, qw, kw,
                                             qg, qrot, krot, vt);
  attn<<<dim3(256), 512, 0, stream>>>(qrot, krot, vt, qg, ctxg);
  gemm_out<<<dim3(16, 16), 256, 0, stream>>>(ctxg, Wob, out);
}